// Round 9
// baseline (301.307 us; speedup 1.0000x reference)
//
#include <hip/hip_runtime.h>
#include <cstddef>

using u16 = unsigned short;
typedef __attribute__((ext_vector_type(8))) short bf16x8;
typedef __attribute__((ext_vector_type(4))) short bf16x4;
typedef __attribute__((ext_vector_type(4))) float f32x4;

constexpr int kB = 4, kL = 256, kR = 64, kH = 768, kTE = 100;
constexpr size_t HH = (size_t)kH * kH;

// ---- output offsets (floats) in return order ----
constexpr size_t OFF_FSS = 0;
constexpr size_t OFF_FSE = OFF_FSS + kB * kL;
constexpr size_t OFF_FOS = OFF_FSE + kB * kL;
constexpr size_t OFF_FOE = OFF_FOS + (size_t)kB * kL * kR;
constexpr size_t OFF_BOS = OFF_FOE + (size_t)kB * kL * kR;
constexpr size_t OFF_BOE = OFF_BOS + kB * kL;
constexpr size_t OFF_BSS = OFF_BOE + kB * kL;
constexpr size_t OFF_BSE = OFF_BSS + (size_t)kB * kL * kR;

// ---- workspace layout (float units), no aliasing ----
constexpr size_t WS_WTALL   = 0;                                   // 10xHH u16 (2..7 used)
constexpr size_t WS_RPROJT  = WS_WTALL   + 10 * HH / 2;            // 768x128 u16
constexpr size_t WS_EMBSB   = WS_RPROJT  + (768 * 128) / 2;        // 1024x768 u16
constexpr size_t WS_RELEMBB = WS_EMBSB   + (1024 * 768) / 2;       // 64x768 u16
constexpr size_t WS_HGSB    = WS_RELEMBB + (64 * 768) / 2;         // 4x768 u16
constexpr size_t WS_RTRANSB = WS_HGSB    + (4 * 768) / 2;          // 64x128 u16
constexpr size_t WS_FPADB   = WS_RTRANSB + (64 * 128) / 2;         // 1024x768 u16
constexpr size_t WS_BPADB   = WS_FPADB   + (1024 * 768) / 2;       // 1024x768 u16
constexpr size_t WS_BRELB   = WS_BPADB   + (1024 * 768) / 2;       // 64x768 u16
constexpr size_t WS_TOKPB   = WS_BRELB   + (64 * 768) / 2;         // 2x1024x768 u16
constexpr size_t WS_RELPF   = WS_TOKPB   + (2 * 1024 * 768) / 2;   // 64x768 f32
constexpr size_t WS_RELPB   = WS_RELPF   + 64 * 768;
constexpr size_t WS_HGPF    = WS_RELPB   + 64 * 768;               // 4x768 f32
constexpr size_t WS_HGPB    = WS_HGPF    + 4 * 768;
constexpr size_t WS_DD      = WS_HGPB    + 4 * 768;                // 4x1024 f32 (d4..d7)
constexpr size_t WS_UA      = WS_DD      + 4 * 1024;               // 4x768 f32
constexpr size_t WS_UB      = WS_UA      + 4 * 768;                // 4x768 f32
constexpr size_t WS_CC      = WS_UB      + 4 * 768;                // 8 f32
constexpr size_t WS_FMASK   = WS_CC      + 8;
constexpr size_t WS_BMASK   = WS_FMASK   + 1024;
constexpr size_t WS_T4      = WS_BMASK   + 1024;
constexpr size_t WS_T5      = WS_T4 + 1024;
constexpr size_t WS_T6      = WS_T5 + 1024;
constexpr size_t WS_T7      = WS_T6 + 1024;
constexpr size_t WS_C4      = WS_T7 + 1024;
constexpr size_t WS_C5      = WS_C4 + 256;
constexpr size_t WS_C6      = WS_C5 + 256;
constexpr size_t WS_C7      = WS_C6 + 256;

__device__ inline float fast_rcp(float x) {
#if __has_builtin(__builtin_amdgcn_rcpf)
    return __builtin_amdgcn_rcpf(x);
#else
    return 1.f / x;
#endif
}
__device__ inline float fast_exp2(float x) {
#if __has_builtin(__builtin_amdgcn_exp2f)
    return __builtin_amdgcn_exp2f(x);
#else
    return __exp2f(x);
#endif
}
__device__ inline u16 f2bf(float x) {   // RNE
    union { float f; unsigned u; } v; v.f = x;
    unsigned r = v.u + 0x7FFFu + ((v.u >> 16) & 1u);
    return (u16)(r >> 16);
}
__device__ inline float bf2f(u16 x) {
    union { unsigned u; float f; } v; v.u = ((unsigned)x) << 16;
    return v.f;
}

// ---- 1. mega-prep: logits(+d4..7 +embsB), Wm transposes, GEMVs, casts, cc ----
// block ranges: [0,1024) logits | [1024,1912) prep_w | [1912,3448) gemv
//               [3448,3512) relemb | [3512,3516) hgs | [3516,3580) rtrans | [3580,3588) cc
__global__ __launch_bounds__(256) void k_prep_all(
        const float* __restrict__ embs, const float* __restrict__ rel_embs,
        const float* __restrict__ h_gs, const float* __restrict__ rel_transe,
        const float* __restrict__ fc_w, const float* __restrict__ fc_b,
        const float* __restrict__ Wm, const float* __restrict__ Wb,
        const float* __restrict__ rproj_w,
        float* __restrict__ out, u16* __restrict__ embsB,
        u16* __restrict__ relembB, u16* __restrict__ hgsB, u16* __restrict__ rtransB,
        u16* __restrict__ WtAll, u16* __restrict__ rprojT,
        float* __restrict__ uA, float* __restrict__ uB, float* __restrict__ cc,
        float* __restrict__ dd)
{
    __shared__ float sh[64 * 65];
    int bx = blockIdx.x, t = threadIdx.x;
    if (bx < 1024) {
        // per-token: embsB cast + 8 dots (4 exact logits, 4 d-vectors)
        int tok = bx;
        const float* e = embs + (size_t)tok * kH;
        float s[8] = {0, 0, 0, 0, 0, 0, 0, 0};
        for (int h = t; h < kH; h += 256) {
            float x = e[h];
            embsB[(size_t)tok * kH + h] = f2bf(x);
#pragma unroll
            for (int j = 0; j < 8; j++) s[j] += x * fc_w[j * kH + h];
        }
#pragma unroll
        for (int off = 32; off; off >>= 1)
#pragma unroll
            for (int j = 0; j < 8; j++) s[j] += __shfl_down(s[j], off, 64);
        float(*red)[4] = (float(*)[4])sh;
        int wid = t >> 6;
        if ((t & 63) == 0) {
#pragma unroll
            for (int j = 0; j < 8; j++) red[j][wid] = s[j];
        }
        __syncthreads();
        if (t == 0) {
            float r[8];
#pragma unroll
            for (int j = 0; j < 8; j++) r[j] = red[j][0] + red[j][1] + red[j][2] + red[j][3];
            out[OFF_FSS + tok] = r[0] + fc_b[0];
            out[OFF_FSE + tok] = r[1] + fc_b[1];
            out[OFF_BOS + tok] = r[2] + fc_b[2];
            out[OFF_BOE + tok] = r[3] + fc_b[3];
            dd[0 * 1024 + tok] = r[4];
            dd[1 * 1024 + tok] = r[5];
            dd[2 * 1024 + tok] = r[6];
            dd[3 * 1024 + tok] = r[7];
        }
    } else if (bx < 1912) {
        // weight transpose (Wm2..7 + rproj)
        int px = bx - 1024;
        float(*tl)[65] = (float(*)[65])sh;
        const float* src; u16* dst; int kt, nt, dstStride, srcRows;
        if (px < 864) {
            int mi = 2 + px / 144, tile = px % 144;
            kt = (tile / 12) * 64; nt = (tile % 12) * 64;
            src = Wm + (size_t)mi * HH; dst = WtAll + (size_t)mi * HH;
            dstStride = kH; srcRows = kH;
        } else {
            int tt = px - 864;
            kt = (tt / 12) * 64; nt = (tt % 12) * 64;
            src = rproj_w; dst = rprojT; dstStride = 128; srcRows = kTE;
        }
        int r = t >> 2, cq = (t & 3) * 16;
        int row = kt + r;
#pragma unroll
        for (int q = 0; q < 4; q++) {
            float4 v = make_float4(0.f, 0.f, 0.f, 0.f);
            if (row < srcRows) v = *(const float4*)(src + (size_t)row * kH + nt + cq + q * 4);
            tl[r][cq + q * 4 + 0] = v.x;
            tl[r][cq + q * 4 + 1] = v.y;
            tl[r][cq + q * 4 + 2] = v.z;
            tl[r][cq + q * 4 + 3] = v.w;
        }
        __syncthreads();
        u16* drow = dst + (size_t)(nt + r) * dstStride + kt + cq;
#pragma unroll
        for (int j = 0; j < 16; j++) drow[j] = f2bf(tl[cq + j][r]);
    } else if (bx < 3448) {
        // GEMVs: uA[j]=Wm{0,0,1,1}@w{4..7}; uB[j]=Wm{8,8,9,9}@w{4..7}+w
        int gx = bx - 1912;
        int j = gx / 192;
        int wid = t >> 6, lane = t & 63;
        int row = (gx % 192) * 4 + wid;
        const int wmI[8] = {0, 0, 1, 1, 8, 8, 9, 9};
        const int fcI[8] = {4, 5, 6, 7, 4, 5, 6, 7};
        const float* W = Wm + (size_t)wmI[j] * HH + (size_t)row * kH;
        const float* w = fc_w + (size_t)fcI[j] * kH;
        float s = 0.f;
        for (int c = lane; c < kH; c += 64) s += W[c] * w[c];
#pragma unroll
        for (int off = 32; off; off >>= 1) s += __shfl_xor(s, off, 64);
        if (lane == 0) {
            if (j < 4) uA[j * kH + row] = s;
            else       uB[(j - 4) * kH + row] = s + w[row];
        }
    } else if (bx < 3512) {
        int r = bx - 3448;
        for (int h = t; h < kH; h += 256) relembB[r * kH + h] = f2bf(rel_embs[r * kH + h]);
    } else if (bx < 3516) {
        int r = bx - 3512;
        for (int h = t; h < kH; h += 256) hgsB[r * kH + h] = f2bf(h_gs[r * kH + h]);
    } else if (bx < 3580) {
        int r = bx - 3516;
        if (t < 128) rtransB[r * 128 + t] = (t < kTE) ? f2bf(rel_transe[r * kTE + t]) : (u16)0;
    } else {
        // cc[j] = Wb[{0,0,1,1,8,8,9,9}[j]] . fc_w[{4,5,6,7,...}[j]]
        int j = bx - 3580;
        const int wbI[8] = {0, 0, 1, 1, 8, 8, 9, 9};
        const int fcI[8] = {4, 5, 6, 7, 4, 5, 6, 7};
        const float* wb = Wb + (size_t)wbI[j] * kH;
        const float* w  = fc_w + (size_t)fcI[j] * kH;
        float s = 0.f;
        for (int h = t; h < kH; h += 256) s += wb[h] * w[h];
#pragma unroll
        for (int off = 32; off; off >>= 1) s += __shfl_down(s, off, 64);
        int wid = t >> 6;
        if ((t & 63) == 0) sh[wid] = s;
        __syncthreads();
        if (t == 0) cc[j] = sh[0] + sh[1] + sh[2] + sh[3];
    }
}

// ---- 2. span extraction: meta scan + span means, fused (8 blocks) ----
__global__ __launch_bounds__(256) void k_extract(const float* __restrict__ out,
        const float* __restrict__ embs,
        float* __restrict__ fmask, float* __restrict__ bmask,
        u16* __restrict__ fpadB, u16* __restrict__ bpadB)
{
    int which = blockIdx.x >> 2;
    int b = blockIdx.x & 3;
    int i = threadIdx.x;
    const float* slog = out + (which ? OFF_BOS : OFF_FSS) + (size_t)b * kL;
    const float* elog = out + (which ? OFF_BOE : OFF_FSE) + (size_t)b * kL;
    float sv = slog[i], ev = elog[i];
    bool st = (1.f / (1.f + __expf(-sv)) > 0.5f);
    bool en = (1.f / (1.f + __expf(-ev)) > 0.5f);

    __shared__ int sm[kL];
    __shared__ int ps[kL];
    __shared__ int stf[kL];
    stf[i] = st ? 1 : 0;
    sm[i] = en ? i : kL;
    __syncthreads();
    for (int step = 1; step < kL; step <<= 1) {  // suffix min
        int v = (i + step < kL) ? sm[i + step] : kL;
        __syncthreads();
        sm[i] = min(sm[i], v);
        __syncthreads();
    }
    ps[i] = (stf[i] && sm[i] < kL) ? 1 : 0;
    __syncthreads();
    for (int step = 1; step < kL; step <<= 1) {  // inclusive prefix sum
        int v = (i >= step) ? ps[i - step] : 0;
        __syncthreads();
        ps[i] += v;
        __syncthreads();
    }
    int num = ps[kL - 1];
    (which ? bmask : fmask)[b * kL + i] = (i < num) ? 1.f : 0.f;
    __syncthreads();

    // mean phase: block-uniform serial loop over valid tokens
    u16* padBase = (which ? bpadB : fpadB) + (size_t)b * kL * kH;
    const float* eb = embs + (size_t)b * kL * kH;
    for (int t0 = 0; t0 < kL; t0++) {
        if (!(stf[t0] && sm[t0] < kL)) continue;
        int j = sm[t0];
        int rk = ps[t0] - 1;
        int len = j - t0 + 1;
        float inv = 1.f / (float)len;
        u16* pad = padBase + (size_t)rk * kH;
        for (int h = i; h < kH; h += 256) {
            float s = 0.f;
            for (int row = t0; row <= j; row++) s += eb[(size_t)row * kH + h];
            pad[h] = f2bf(s * inv);
        }
    }
}

// ---- 3. batched MFMA GEMM, 64x128 tile, BK=64, dbuf + reg-prefetch ----
struct GemmJob {
    const u16* A; const u16* Wt; const float* bias;
    float* C; u16* Cbf; const float* rowmask;
    int M; int K; int ldc; int coff;
};
struct GemmBatch { GemmJob j[6]; };

__device__ inline int swz(int row, int slot) {   // short-index into [row][64] layout
    return row * 64 + ((slot ^ (row & 7)) << 3);
}

__global__ __launch_bounds__(256) void k_gemm_mfma(GemmBatch batch)
{
    GemmJob jb = batch.j[blockIdx.z];
    if (blockIdx.x * 64 >= jb.M) return;
    __shared__ short Als[2][64 * 64];      // 16 KB
    __shared__ short Bls[2][128 * 64];     // 32 KB
    int tid = threadIdx.x;
    int m0 = blockIdx.x * 64;
    int n0 = blockIdx.y * 128;
    int w = tid >> 6, lane = tid & 63;
    int wm = (w >> 1) * 32, wn = (w & 1) * 64;
    int lrow = lane & 15, lhi = lane >> 4;
    int arow = tid >> 2, ac0 = (tid & 3) * 2;
    int brow = tid >> 1, bc0 = (tid & 1) * 4;
    int K = jb.K;
    int T = K >> 6;

    f32x4 zero4 = {0.f, 0.f, 0.f, 0.f};
    f32x4 acc[2][4];
#pragma unroll
    for (int i = 0; i < 2; i++)
#pragma unroll
        for (int j = 0; j < 4; j++) acc[i][j] = zero4;

    bf16x8 pa[2], pb[4];

#define LOADT(k0)                                                                 \
    {                                                                             \
        _Pragma("unroll")                                                         \
        for (int q = 0; q < 2; q++) {                                             \
            bf16x8 va;                                                            \
            _Pragma("unroll") for (int z = 0; z < 8; z++) va[z] = 0;              \
            if (m0 + arow < jb.M)                                                 \
                va = *reinterpret_cast<const bf16x8*>(                            \
                    jb.A + (size_t)(m0 + arow) * K + (k0) + (ac0 + q) * 8);       \
            pa[q] = va;                                                           \
        }                                                                         \
        _Pragma("unroll")                                                         \
        for (int q = 0; q < 4; q++)                                               \
            pb[q] = *reinterpret_cast<const bf16x8*>(                             \
                jb.Wt + (size_t)(n0 + brow) * K + (k0) + (bc0 + q) * 8);          \
    }
#define STORET(buf)                                                               \
    {                                                                             \
        _Pragma("unroll")                                                         \
        for (int q = 0; q < 2; q++)                                               \
            *reinterpret_cast<bf16x8*>(&Als[buf][swz(arow, ac0 + q)]) = pa[q];    \
        _Pragma("unroll")                                                         \
        for (int q = 0; q < 4; q++)                                               \
            *reinterpret_cast<bf16x8*>(&Bls[buf][swz(brow, bc0 + q)]) = pb[q];    \
    }

    LOADT(0);
    STORET(0);
    __syncthreads();
    int cur = 0;
    for (int t = 0; t < T; t++) {
        if (t + 1 < T) LOADT((t + 1) << 6);
#pragma unroll
        for (int sub = 0; sub < 2; sub++) {
            bf16x8 af[2], bg[4];
#pragma unroll
            for (int i = 0; i < 2; i++)
                af[i] = *reinterpret_cast<const bf16x8*>(
                    &Als[cur][swz(wm + i * 16 + lrow, sub * 4 + lhi)]);
#pragma unroll
            for (int j = 0; j < 4; j++)
                bg[j] = *reinterpret_cast<const bf16x8*>(
                    &Bls[cur][swz(wn + j * 16 + lrow, sub * 4 + lhi)]);
#pragma unroll
            for (int i = 0; i < 2; i++)
#pragma unroll
                for (int j = 0; j < 4; j++)
                    acc[i][j] = __builtin_amdgcn_mfma_f32_16x16x32_bf16(af[i], bg[j], acc[i][j], 0, 0, 0);
        }
        if (t + 1 < T) STORET(cur ^ 1);
        __syncthreads();
        cur ^= 1;
    }
#undef LOADT
#undef STORET

#pragma unroll
    for (int i = 0; i < 2; i++) {
#pragma unroll
        for (int j = 0; j < 4; j++) {
            int n = n0 + wn + j * 16 + lrow;
            float bi = jb.bias[n];
#pragma unroll
            for (int q = 0; q < 4; q++) {
                int m = m0 + wm + i * 16 + lhi * 4 + q;
                if (m < jb.M) {
                    float val = acc[i][j][q] + bi;
                    if (jb.rowmask) val = (jb.rowmask[m] != 0.f) ? val : 0.f;
                    if (jb.C)   jb.C[(size_t)m * jb.ldc + jb.coff + n] = val;
                    if (jb.Cbf) jb.Cbf[(size_t)m * jb.ldc + jb.coff + n] = f2bf(val);
                }
            }
        }
    }
}

// ---- 4. attention: scores + softmax + c-dots fused; block=(which,b,r) ----
__global__ __launch_bounds__(512) void k_score(const u16* __restrict__ tokpB,
        const float* __restrict__ relpf, const float* __restrict__ relpb,
        const float* __restrict__ hgpf, const float* __restrict__ hgpb,
        const float* __restrict__ V_w, const float* __restrict__ V_b,
        const float* __restrict__ dd,
        float* __restrict__ c4, float* __restrict__ c5,
        float* __restrict__ c6, float* __restrict__ c7)
{
    constexpr float C = 2.8853900817779268f;   // 2*log2(e)
    int idx = blockIdx.x;            // 512
    int which = idx >> 8, b = (idx >> 6) & 3, r = idx & 63;
    int tid = threadIdx.x;
    int wid = tid >> 6, lane = tid & 63;
    int h0 = lane * 12;
    const float* relp = (which ? relpb : relpf) + (size_t)r * kH + h0;
    const float* hgp  = (which ? hgpb : hgpf) + (size_t)b * kH + h0;
    const float* vw   = V_w + h0;

    __shared__ float sc[kL];
    __shared__ float red2[2][8];

    float av2[12], w2[12], wsum = 0.f;
#pragma unroll
    for (int j = 0; j < 12; j++) {
        av2[j] = C * (relp[j] + hgp[j]);
        float wv = vw[j];
        w2[j] = -2.f * wv;
        wsum += wv;
    }
    float vb = V_b[0];
    const u16* base = tokpB + ((size_t)which * (kB * kL) + b * kL) * kH + h0;

    int l0 = wid * 32;
    bf16x4 t0 = *reinterpret_cast<const bf16x4*>(base + (size_t)l0 * kH);
    bf16x4 t1 = *reinterpret_cast<const bf16x4*>(base + (size_t)l0 * kH + 4);
    bf16x4 t2 = *reinterpret_cast<const bf16x4*>(base + (size_t)l0 * kH + 8);
    for (int l = l0; l < l0 + 32; l++) {
        bf16x4 n0, n1, n2;
        if (l + 1 < l0 + 32) {
            const u16* nrow = base + (size_t)(l + 1) * kH;
            n0 = *reinterpret_cast<const bf16x4*>(nrow);
            n1 = *reinterpret_cast<const bf16x4*>(nrow + 4);
            n2 = *reinterpret_cast<const bf16x4*>(nrow + 8);
        }
        float acc = wsum;
#pragma unroll
        for (int j = 0; j < 4; j++) {
            float e0 = fast_exp2(fmaf(bf2f((u16)t0[j]), C, av2[j]));
            acc = fmaf(w2[j], fast_rcp(e0 + 1.f), acc);
            float e1 = fast_exp2(fmaf(bf2f((u16)t1[j]), C, av2[4 + j]));
            acc = fmaf(w2[4 + j], fast_rcp(e1 + 1.f), acc);
            float e2 = fast_exp2(fmaf(bf2f((u16)t2[j]), C, av2[8 + j]));
            acc = fmaf(w2[8 + j], fast_rcp(e2 + 1.f), acc);
        }
#pragma unroll
        for (int off = 32; off; off >>= 1) acc += __shfl_xor(acc, off, 64);
        if (lane == 0) sc[l] = acc + vb;
        t0 = n0; t1 = n1; t2 = n2;
    }
    __syncthreads();

    // softmax over sc[0..255] + c-dots (A never materialized)
    int l = tid & 255;
    bool act = tid < 256;
    float x = act ? sc[l] : -3.4e38f;
    float m = x;
#pragma unroll
    for (int off = 32; off; off >>= 1) m = fmaxf(m, __shfl_xor(m, off, 64));
    if (lane == 0) red2[0][wid] = m;
    __syncthreads();
    m = fmaxf(fmaxf(red2[0][0], red2[0][1]), fmaxf(red2[0][2], red2[0][3]));
    float p = act ? __expf(x - m) : 0.f;
    float s = p;
#pragma unroll
    for (int off = 32; off; off >>= 1) s += __shfl_xor(s, off, 64);
    __syncthreads();
    if (lane == 0) red2[0][wid] = s;
    __syncthreads();
    s = red2[0][0] + red2[0][1] + red2[0][2] + red2[0][3];
    float a = p / s;
    const float* dA = dd + (size_t)(which ? 2 : 0) * 1024 + b * 256;
    const float* dB = dd + (size_t)(which ? 3 : 1) * 1024 + b * 256;
    float q0 = act ? a * dA[l] : 0.f;
    float q1 = act ? a * dB[l] : 0.f;
#pragma unroll
    for (int off = 32; off; off >>= 1) {
        q0 += __shfl_xor(q0, off, 64);
        q1 += __shfl_xor(q1, off, 64);
    }
    __syncthreads();
    if (lane == 0) { red2[0][wid] = q0; red2[1][wid] = q1; }
    __syncthreads();
    if (tid == 0) {
        float r0 = red2[0][0] + red2[0][1] + red2[0][2] + red2[0][3];
        float r1 = red2[1][0] + red2[1][1] + red2[1][2] + red2[1][3];
        if (which) { c6[b * kR + r] = r0; c7[b * kR + r] = r1; }
        else       { c4[b * kR + r] = r0; c5[b * kR + r] = r1; }
    }
}

// ---- 5. t vectors via GEMV decomposition ----
__global__ __launch_bounds__(256) void k_t(const float* __restrict__ embs,
        const u16* __restrict__ fpadB, const u16* __restrict__ bpadB,
        const float* __restrict__ uA, const float* __restrict__ uB,
        const float* __restrict__ cc,
        const float* __restrict__ fmask, const float* __restrict__ bmask,
        float* __restrict__ t4, float* __restrict__ t5,
        float* __restrict__ t6, float* __restrict__ t7)
{
    int t = blockIdx.x;               // 1024
    size_t base = (size_t)t * kH;
    float a4 = 0, a5 = 0, a6 = 0, a7 = 0, f4 = 0, f5 = 0, b6 = 0, b7 = 0;
    for (int h = threadIdx.x; h < kH; h += 256) {
        float e = embs[base + h];
        a4 += e * uB[h];
        a5 += e * uB[kH + h];
        a6 += e * uB[2 * kH + h];
        a7 += e * uB[3 * kH + h];
        float fp = bf2f(fpadB[base + h]);
        f4 += fp * uA[h];
        f5 += fp * uA[kH + h];
        float bp = bf2f(bpadB[base + h]);
        b6 += bp * uA[2 * kH + h];
        b7 += bp * uA[3 * kH + h];
    }
#pragma unroll
    for (int off = 32; off; off >>= 1) {
        a4 += __shfl_down(a4, off, 64);
        a5 += __shfl_down(a5, off, 64);
        a6 += __shfl_down(a6, off, 64);
        a7 += __shfl_down(a7, off, 64);
        f4 += __shfl_down(f4, off, 64);
        f5 += __shfl_down(f5, off, 64);
        b6 += __shfl_down(b6, off, 64);
        b7 += __shfl_down(b7, off, 64);
    }
    __shared__ float red[8][4];
    int wid = threadIdx.x >> 6;
    if ((threadIdx.x & 63) == 0) {
        red[0][wid] = a4; red[1][wid] = a5; red[2][wid] = a6; red[3][wid] = a7;
        red[4][wid] = f4; red[5][wid] = f5; red[6][wid] = b6; red[7][wid] = b7;
    }
    __syncthreads();
    if (threadIdx.x == 0) {
        float ra4 = red[0][0] + red[0][1] + red[0][2] + red[0][3];
        float ra5 = red[1][0] + red[1][1] + red[1][2] + red[1][3];
        float ra6 = red[2][0] + red[2][1] + red[2][2] + red[2][3];
        float ra7 = red[3][0] + red[3][1] + red[3][2] + red[3][3];
        float rf4 = red[4][0] + red[4][1] + red[4][2] + red[4][3];
        float rf5 = red[5][0] + red[5][1] + red[5][2] + red[5][3];
        float rb6 = red[6][0] + red[6][1] + red[6][2] + red[6][3];
        float rb7 = red[7][0] + red[7][1] + red[7][2] + red[7][3];
        bool mf = fmask[t] != 0.f, mb = bmask[t] != 0.f;
        // SELECT: masked pad rows may hold stale/poison bits -> never multiply
        t4[t] = (mf ? (rf4 + cc[0]) : 0.f) + ra4 + cc[4];
        t5[t] = (mf ? (rf5 + cc[1]) : 0.f) + ra5 + cc[5];
        t6[t] = (mb ? (rb6 + cc[2]) : 0.f) + ra6 + cc[6];
        t7[t] = (mb ? (rb7 + cc[3]) : 0.f) + ra7 + cc[7];
    }
}

// ---- 6. broadcast-add final pair logits ----
__global__ __launch_bounds__(64) void k_final(const float* __restrict__ t4,
        const float* __restrict__ t5, const float* __restrict__ t6,
        const float* __restrict__ t7, const float* __restrict__ c4,
        const float* __restrict__ c5, const float* __restrict__ c6,
        const float* __restrict__ c7, const float* __restrict__ fc_b,
        float* __restrict__ out)
{
    int which = blockIdx.x >> 10;
    int t = blockIdx.x & 1023;
    int b = t >> 8;
    int r = threadIdx.x;
    if (!which) {
        out[OFF_FOS + (size_t)t * kR + r] = t4[t] + c4[b * kR + r] + fc_b[4];
        out[OFF_FOE + (size_t)t * kR + r] = t5[t] + c5[b * kR + r] + fc_b[5];
    } else {
        out[OFF_BSS + (size_t)t * kR + r] = t6[t] + c6[b * kR + r] + fc_b[6];
        out[OFF_BSE + (size_t)t * kR + r] = t7[t] + c7[b * kR + r] + fc_b[7];
    }
}

extern "C" void kernel_launch(void* const* d_in, const int* in_sizes, int n_in,
                              void* d_out, int out_size, void* d_ws, size_t ws_size,
                              hipStream_t stream)
{
    const float* embs       = (const float*)d_in[0];
    const float* h_gs       = (const float*)d_in[1];
    const float* rel_embs   = (const float*)d_in[2];
    const float* rel_transe = (const float*)d_in[3];
    const float* fc_w       = (const float*)d_in[4];
    const float* fc_b       = (const float*)d_in[5];
    const float* Wm         = (const float*)d_in[6];
    const float* Wb         = (const float*)d_in[7];
    const float* V_w        = (const float*)d_in[8];
    const float* V_b        = (const float*)d_in[9];
    const float* rproj_w    = (const float*)d_in[10];
    const float* rproj_b    = (const float*)d_in[11];
    float* out = (float*)d_out;
    float* ws  = (float*)d_ws;

    u16* WtAll   = (u16*)(ws + WS_WTALL);
    u16* rprojT  = (u16*)(ws + WS_RPROJT);
    u16* embsB   = (u16*)(ws + WS_EMBSB);
    u16* relembB = (u16*)(ws + WS_RELEMBB);
    u16* hgsB    = (u16*)(ws + WS_HGSB);
    u16* rtransB = (u16*)(ws + WS_RTRANSB);
    u16* fpadB   = (u16*)(ws + WS_FPADB);
    u16* bpadB   = (u16*)(ws + WS_BPADB);
    u16* brelB   = (u16*)(ws + WS_BRELB);
    u16* tokpB   = (u16*)(ws + WS_TOKPB);
    float* relpf = ws + WS_RELPF;
    float* relpb = ws + WS_RELPB;
    float* hgpf  = ws + WS_HGPF;
    float* hgpb  = ws + WS_HGPB;
    float* dd    = ws + WS_DD;
    float* uA    = ws + WS_UA;
    float* uB    = ws + WS_UB;
    float* cc    = ws + WS_CC;
    float* fmask = ws + WS_FMASK;
    float* bmask = ws + WS_BMASK;
    float* t4 = ws + WS_T4; float* t5 = ws + WS_T5;
    float* t6 = ws + WS_T6; float* t7 = ws + WS_T7;
    float* c4 = ws + WS_C4; float* c5 = ws + WS_C5;
    float* c6 = ws + WS_C6; float* c7 = ws + WS_C7;

    // 1. mega-prep (everything depending only on inputs)
    k_prep_all<<<3588, 256, 0, stream>>>(embs, rel_embs, h_gs, rel_transe,
        fc_w, fc_b, Wm, Wb, rproj_w,
        out, embsB, relembB, hgsB, rtransB, WtAll, rprojT, uA, uB, cc, dd);

    // 2. span extraction (meta + means)
    k_extract<<<2 * kB, 256, 0, stream>>>(out, embs, fmask, bmask, fpadB, bpadB);

    // 3. t vectors
    k_t<<<kB * kL, 256, 0, stream>>>(embs, fpadB, bpadB, uA, uB, cc, fmask, bmask,
                                     t4, t5, t6, t7);

    // 4. gemmA: relpf, hgpf, hgpb, brel, tokp x2
    {
        GemmBatch bt;
        bt.j[0] = { relembB, WtAll + 2 * HH, Wb + 2 * kH, relpf, nullptr, nullptr, kR, kH, kH, 0 };
        bt.j[1] = { hgsB,    WtAll + 3 * HH, Wb + 3 * kH, hgpf,  nullptr, nullptr, kB, kH, kH, 0 };
        bt.j[2] = { hgsB,    WtAll + 6 * HH, Wb + 6 * kH, hgpb,  nullptr, nullptr, kB, kH, kH, 0 };
        bt.j[3] = { rtransB, rprojT,         rproj_b,     nullptr, brelB, nullptr, kR, 128, kH, 0 };
        bt.j[4] = { embsB,   WtAll + 4 * HH, Wb + 4 * kH, nullptr, tokpB,            nullptr, kB * kL, kH, kH, 0 };
        bt.j[5] = { embsB,   WtAll + 7 * HH, Wb + 7 * kH, nullptr, tokpB + (size_t)kB * kL * kH, nullptr, kB * kL, kH, kH, 0 };
        k_gemm_mfma<<<dim3(16, 6, 6), 256, 0, stream>>>(bt);
    }
    // 5. gemmB: relpb = brel @ Wm5
    {
        GemmBatch bt;
        bt.j[0] = { brelB, WtAll + 5 * HH, Wb + 5 * kH, relpb, nullptr, nullptr, kR, kH, kH, 0 };
        for (int z = 1; z < 6; z++) bt.j[z] = bt.j[0];
        k_gemm_mfma<<<dim3(1, 6, 1), 256, 0, stream>>>(bt);
    }

    // 6. fused scores + softmax + c-dots
    k_score<<<512, 512, 0, stream>>>(tokpB, relpf, relpb, hgpf, hgpb, V_w, V_b,
                                     dd, c4, c5, c6, c7);

    // 7. final broadcast-add
    k_final<<<2 * kB * kL, 64, 0, stream>>>(t4, t5, t6, t7, c4, c5, c6, c7, fc_b, out);
}

// Round 10
// 101.830 us; speedup vs baseline: 2.9589x; 2.9589x over previous
//
#include <hip/hip_runtime.h>
#include <cstddef>

using u16 = unsigned short;
typedef __attribute__((ext_vector_type(8))) short bf16x8;
typedef __attribute__((ext_vector_type(4))) short bf16x4;
typedef __attribute__((ext_vector_type(4))) float f32x4;

constexpr int kB = 4, kL = 256, kR = 64, kH = 768, kTE = 100;
constexpr size_t HH = (size_t)kH * kH;

// ---- output offsets (floats) in return order ----
constexpr size_t OFF_FSS = 0;
constexpr size_t OFF_FSE = OFF_FSS + kB * kL;
constexpr size_t OFF_FOS = OFF_FSE + kB * kL;
constexpr size_t OFF_FOE = OFF_FOS + (size_t)kB * kL * kR;
constexpr size_t OFF_BOS = OFF_FOE + (size_t)kB * kL * kR;
constexpr size_t OFF_BOE = OFF_BOS + kB * kL;
constexpr size_t OFF_BSS = OFF_BOE + kB * kL;
constexpr size_t OFF_BSE = OFF_BSS + (size_t)kB * kL * kR;

// ---- workspace layout (float units), no aliasing ----
constexpr size_t WS_WTALL   = 0;                                   // 10xHH u16 (2..7 used)
constexpr size_t WS_RPROJT  = WS_WTALL   + 10 * HH / 2;            // 768x128 u16
constexpr size_t WS_EMBSB   = WS_RPROJT  + (768 * 128) / 2;        // 1024x768 u16
constexpr size_t WS_RELEMBB = WS_EMBSB   + (1024 * 768) / 2;       // 64x768 u16
constexpr size_t WS_HGSB    = WS_RELEMBB + (64 * 768) / 2;         // 4x768 u16
constexpr size_t WS_RTRANSB = WS_HGSB    + (4 * 768) / 2;          // 64x128 u16
constexpr size_t WS_FPADB   = WS_RTRANSB + (64 * 128) / 2;         // 1024x768 u16
constexpr size_t WS_BPADB   = WS_FPADB   + (1024 * 768) / 2;       // 1024x768 u16
constexpr size_t WS_BRELB   = WS_BPADB   + (1024 * 768) / 2;       // 64x768 u16
constexpr size_t WS_TOKPB   = WS_BRELB   + (64 * 768) / 2;         // 2x1024x768 u16
constexpr size_t WS_RELPF   = WS_TOKPB   + (2 * 1024 * 768) / 2;   // 64x768 f32
constexpr size_t WS_RELPB   = WS_RELPF   + 64 * 768;
constexpr size_t WS_HGPF    = WS_RELPB   + 64 * 768;               // 4x768 f32
constexpr size_t WS_HGPB    = WS_HGPF    + 4 * 768;
constexpr size_t WS_DD      = WS_HGPB    + 4 * 768;                // 4x1024 f32 (d4..d7)
constexpr size_t WS_UA      = WS_DD      + 4 * 1024;               // 4x768 f32
constexpr size_t WS_UB      = WS_UA      + 4 * 768;                // 4x768 f32
constexpr size_t WS_CC      = WS_UB      + 4 * 768;                // 8 f32
constexpr size_t WS_FMASK   = WS_CC      + 8;
constexpr size_t WS_BMASK   = WS_FMASK   + 1024;
constexpr size_t WS_T4      = WS_BMASK   + 1024;
constexpr size_t WS_T5      = WS_T4 + 1024;
constexpr size_t WS_T6      = WS_T5 + 1024;
constexpr size_t WS_T7      = WS_T6 + 1024;
constexpr size_t WS_C4      = WS_T7 + 1024;
constexpr size_t WS_C5      = WS_C4 + 256;
constexpr size_t WS_C6      = WS_C5 + 256;
constexpr size_t WS_C7      = WS_C6 + 256;
constexpr size_t WS_AUX     = WS_C7 + 256;      // int region: jbuf/rankbuf/validbuf

__device__ inline float fast_rcp(float x) {
#if __has_builtin(__builtin_amdgcn_rcpf)
    return __builtin_amdgcn_rcpf(x);
#else
    return 1.f / x;
#endif
}
__device__ inline float fast_exp2(float x) {
#if __has_builtin(__builtin_amdgcn_exp2f)
    return __builtin_amdgcn_exp2f(x);
#else
    return __exp2f(x);
#endif
}
__device__ inline u16 f2bf(float x) {   // RNE
    union { float f; unsigned u; } v; v.f = x;
    unsigned r = v.u + 0x7FFFu + ((v.u >> 16) & 1u);
    return (u16)(r >> 16);
}
__device__ inline float bf2f(u16 x) {
    union { unsigned u; float f; } v; v.u = ((unsigned)x) << 16;
    return v.f;
}

// ---- 1. mega-prep: logits(+d4..7 +embsB), Wm transposes, GEMVs, casts, cc ----
__global__ __launch_bounds__(256) void k_prep_all(
        const float* __restrict__ embs, const float* __restrict__ rel_embs,
        const float* __restrict__ h_gs, const float* __restrict__ rel_transe,
        const float* __restrict__ fc_w, const float* __restrict__ fc_b,
        const float* __restrict__ Wm, const float* __restrict__ Wb,
        const float* __restrict__ rproj_w,
        float* __restrict__ out, u16* __restrict__ embsB,
        u16* __restrict__ relembB, u16* __restrict__ hgsB, u16* __restrict__ rtransB,
        u16* __restrict__ WtAll, u16* __restrict__ rprojT,
        float* __restrict__ uA, float* __restrict__ uB, float* __restrict__ cc,
        float* __restrict__ dd)
{
    __shared__ float sh[64 * 65];
    int bx = blockIdx.x, t = threadIdx.x;
    if (bx < 1024) {
        // per-token: embsB cast + 8 dots (4 exact logits, 4 d-vectors)
        int tok = bx;
        const float* e = embs + (size_t)tok * kH;
        float s[8] = {0, 0, 0, 0, 0, 0, 0, 0};
        for (int h = t; h < kH; h += 256) {
            float x = e[h];
            embsB[(size_t)tok * kH + h] = f2bf(x);
#pragma unroll
            for (int j = 0; j < 8; j++) s[j] += x * fc_w[j * kH + h];
        }
#pragma unroll
        for (int off = 32; off; off >>= 1)
#pragma unroll
            for (int j = 0; j < 8; j++) s[j] += __shfl_down(s[j], off, 64);
        float(*red)[4] = (float(*)[4])sh;
        int wid = t >> 6;
        if ((t & 63) == 0) {
#pragma unroll
            for (int j = 0; j < 8; j++) red[j][wid] = s[j];
        }
        __syncthreads();
        if (t == 0) {
            float r[8];
#pragma unroll
            for (int j = 0; j < 8; j++) r[j] = red[j][0] + red[j][1] + red[j][2] + red[j][3];
            out[OFF_FSS + tok] = r[0] + fc_b[0];
            out[OFF_FSE + tok] = r[1] + fc_b[1];
            out[OFF_BOS + tok] = r[2] + fc_b[2];
            out[OFF_BOE + tok] = r[3] + fc_b[3];
            dd[0 * 1024 + tok] = r[4];
            dd[1 * 1024 + tok] = r[5];
            dd[2 * 1024 + tok] = r[6];
            dd[3 * 1024 + tok] = r[7];
        }
    } else if (bx < 1912) {
        // weight transpose (Wm2..7 + rproj)
        int px = bx - 1024;
        float(*tl)[65] = (float(*)[65])sh;
        const float* src; u16* dst; int kt, nt, dstStride, srcRows;
        if (px < 864) {
            int mi = 2 + px / 144, tile = px % 144;
            kt = (tile / 12) * 64; nt = (tile % 12) * 64;
            src = Wm + (size_t)mi * HH; dst = WtAll + (size_t)mi * HH;
            dstStride = kH; srcRows = kH;
        } else {
            int tt = px - 864;
            kt = (tt / 12) * 64; nt = (tt % 12) * 64;
            src = rproj_w; dst = rprojT; dstStride = 128; srcRows = kTE;
        }
        int r = t >> 2, cq = (t & 3) * 16;
        int row = kt + r;
#pragma unroll
        for (int q = 0; q < 4; q++) {
            float4 v = make_float4(0.f, 0.f, 0.f, 0.f);
            if (row < srcRows) v = *(const float4*)(src + (size_t)row * kH + nt + cq + q * 4);
            tl[r][cq + q * 4 + 0] = v.x;
            tl[r][cq + q * 4 + 1] = v.y;
            tl[r][cq + q * 4 + 2] = v.z;
            tl[r][cq + q * 4 + 3] = v.w;
        }
        __syncthreads();
        u16* drow = dst + (size_t)(nt + r) * dstStride + kt + cq;
#pragma unroll
        for (int j = 0; j < 16; j++) drow[j] = f2bf(tl[cq + j][r]);
    } else if (bx < 3448) {
        // GEMVs: uA[j]=Wm{0,0,1,1}@w{4..7}; uB[j]=Wm{8,8,9,9}@w{4..7}+w
        int gx = bx - 1912;
        int j = gx / 192;
        int wid = t >> 6, lane = t & 63;
        int row = (gx % 192) * 4 + wid;
        const int wmI[8] = {0, 0, 1, 1, 8, 8, 9, 9};
        const int fcI[8] = {4, 5, 6, 7, 4, 5, 6, 7};
        const float* W = Wm + (size_t)wmI[j] * HH + (size_t)row * kH;
        const float* w = fc_w + (size_t)fcI[j] * kH;
        float s = 0.f;
        for (int c = lane; c < kH; c += 64) s += W[c] * w[c];
#pragma unroll
        for (int off = 32; off; off >>= 1) s += __shfl_xor(s, off, 64);
        if (lane == 0) {
            if (j < 4) uA[j * kH + row] = s;
            else       uB[(j - 4) * kH + row] = s + w[row];
        }
    } else if (bx < 3512) {
        int r = bx - 3448;
        for (int h = t; h < kH; h += 256) relembB[r * kH + h] = f2bf(rel_embs[r * kH + h]);
    } else if (bx < 3516) {
        int r = bx - 3512;
        for (int h = t; h < kH; h += 256) hgsB[r * kH + h] = f2bf(h_gs[r * kH + h]);
    } else if (bx < 3580) {
        int r = bx - 3516;
        if (t < 128) rtransB[r * 128 + t] = (t < kTE) ? f2bf(rel_transe[r * kTE + t]) : (u16)0;
    } else {
        // cc[j] = Wb[{0,0,1,1,8,8,9,9}[j]] . fc_w[{4,5,6,7,...}[j]]
        int j = bx - 3580;
        const int wbI[8] = {0, 0, 1, 1, 8, 8, 9, 9};
        const int fcI[8] = {4, 5, 6, 7, 4, 5, 6, 7};
        const float* wb = Wb + (size_t)wbI[j] * kH;
        const float* w  = fc_w + (size_t)fcI[j] * kH;
        float s = 0.f;
        for (int h = t; h < kH; h += 256) s += wb[h] * w[h];
#pragma unroll
        for (int off = 32; off; off >>= 1) s += __shfl_down(s, off, 64);
        int wid = t >> 6;
        if ((t & 63) == 0) sh[wid] = s;
        __syncthreads();
        if (t == 0) cc[j] = sh[0] + sh[1] + sh[2] + sh[3];
    }
}

// ---- 2a. span extraction metadata (8 blocks, LDS scans) ----
__global__ __launch_bounds__(256) void k_extract_meta(const float* __restrict__ out,
        int* __restrict__ jbuf, int* __restrict__ rankbuf, int* __restrict__ validbuf,
        float* __restrict__ fmask, float* __restrict__ bmask)
{
    int which = blockIdx.x >> 2;
    int b = blockIdx.x & 3;
    int i = threadIdx.x;
    const float* slog = out + (which ? OFF_BOS : OFF_FSS) + (size_t)b * kL;
    const float* elog = out + (which ? OFF_BOE : OFF_FSE) + (size_t)b * kL;
    float sv = slog[i], ev = elog[i];
    bool st = (1.f / (1.f + __expf(-sv)) > 0.5f);
    bool en = (1.f / (1.f + __expf(-ev)) > 0.5f);

    __shared__ int sm[kL];
    __shared__ int ps[kL];
    sm[i] = en ? i : kL;
    __syncthreads();
    for (int step = 1; step < kL; step <<= 1) {  // suffix min
        int v = (i + step < kL) ? sm[i + step] : kL;
        __syncthreads();
        sm[i] = min(sm[i], v);
        __syncthreads();
    }
    int next_end = sm[i];
    int validi = (st && next_end < kL) ? 1 : 0;
    ps[i] = validi;
    __syncthreads();
    for (int step = 1; step < kL; step <<= 1) {  // inclusive prefix sum
        int v = (i >= step) ? ps[i - step] : 0;
        __syncthreads();
        ps[i] += v;
        __syncthreads();
    }
    int rank = ps[i] - 1;
    int num = ps[kL - 1];
    int gbase = (which * kB + b) * kL + i;
    jbuf[gbase] = min(next_end, kL - 1);
    rankbuf[gbase] = rank;
    validbuf[gbase] = validi;
    (which ? bmask : fmask)[b * kL + i] = (i < num) ? 1.f : 0.f;
}

// ---- 2b. span means packed by rank (2048 blocks, parallel) ----
__global__ __launch_bounds__(256) void k_span_mean(const float* __restrict__ embs,
        const int* __restrict__ jbuf, const int* __restrict__ rankbuf,
        const int* __restrict__ validbuf, u16* __restrict__ fpadB, u16* __restrict__ bpadB)
{
    int idx = blockIdx.x;
    int which = idx >> 10;
    int b = (idx >> 8) & 3;
    int i = idx & 255;
    int gbase = (which * kB + b) * kL + i;
    if (!validbuf[gbase]) return;
    int j = jbuf[gbase];
    int rk = rankbuf[gbase];
    int len = j - i + 1;
    float inv = 1.f / (float)len;
    u16* pad = (which ? bpadB : fpadB) + ((size_t)(b * kL + rk)) * kH;
    const float* e = embs + ((size_t)(b * kL + i)) * kH;
    for (int h = threadIdx.x; h < kH; h += 256) {
        float s = 0.f;
        for (int row = 0; row < len; row++) s += e[(size_t)row * kH + h];
        pad[h] = f2bf(s * inv);
    }
}

// ---- 3. batched MFMA GEMM, 64x128 tile, BK=64, dbuf + reg-prefetch ----
struct GemmJob {
    const u16* A; const u16* Wt; const float* bias;
    float* C; u16* Cbf; const float* rowmask;
    int M; int K; int ldc; int coff;
};
struct GemmBatch { GemmJob j[6]; };

__device__ inline int swz(int row, int slot) {   // short-index into [row][64] layout
    return row * 64 + ((slot ^ (row & 7)) << 3);
}

__global__ __launch_bounds__(256) void k_gemm_mfma(GemmBatch batch)
{
    GemmJob jb = batch.j[blockIdx.z];
    if (blockIdx.x * 64 >= jb.M) return;
    __shared__ short Als[2][64 * 64];      // 16 KB
    __shared__ short Bls[2][128 * 64];     // 32 KB
    int tid = threadIdx.x;
    int m0 = blockIdx.x * 64;
    int n0 = blockIdx.y * 128;
    int w = tid >> 6, lane = tid & 63;
    int wm = (w >> 1) * 32, wn = (w & 1) * 64;
    int lrow = lane & 15, lhi = lane >> 4;
    int arow = tid >> 2, ac0 = (tid & 3) * 2;
    int brow = tid >> 1, bc0 = (tid & 1) * 4;
    int K = jb.K;
    int T = K >> 6;

    f32x4 zero4 = {0.f, 0.f, 0.f, 0.f};
    f32x4 acc[2][4];
#pragma unroll
    for (int i = 0; i < 2; i++)
#pragma unroll
        for (int j = 0; j < 4; j++) acc[i][j] = zero4;

    bf16x8 pa[2], pb[4];

#define LOADT(k0)                                                                 \
    {                                                                             \
        _Pragma("unroll")                                                         \
        for (int q = 0; q < 2; q++) {                                             \
            bf16x8 va;                                                            \
            _Pragma("unroll") for (int z = 0; z < 8; z++) va[z] = 0;              \
            if (m0 + arow < jb.M)                                                 \
                va = *reinterpret_cast<const bf16x8*>(                            \
                    jb.A + (size_t)(m0 + arow) * K + (k0) + (ac0 + q) * 8);       \
            pa[q] = va;                                                           \
        }                                                                         \
        _Pragma("unroll")                                                         \
        for (int q = 0; q < 4; q++)                                               \
            pb[q] = *reinterpret_cast<const bf16x8*>(                             \
                jb.Wt + (size_t)(n0 + brow) * K + (k0) + (bc0 + q) * 8);          \
    }
#define STORET(buf)                                                               \
    {                                                                             \
        _Pragma("unroll")                                                         \
        for (int q = 0; q < 2; q++)                                               \
            *reinterpret_cast<bf16x8*>(&Als[buf][swz(arow, ac0 + q)]) = pa[q];    \
        _Pragma("unroll")                                                         \
        for (int q = 0; q < 4; q++)                                               \
            *reinterpret_cast<bf16x8*>(&Bls[buf][swz(brow, bc0 + q)]) = pb[q];    \
    }

    LOADT(0);
    STORET(0);
    __syncthreads();
    int cur = 0;
    for (int t = 0; t < T; t++) {
        if (t + 1 < T) LOADT((t + 1) << 6);
#pragma unroll
        for (int sub = 0; sub < 2; sub++) {
            bf16x8 af[2], bg[4];
#pragma unroll
            for (int i = 0; i < 2; i++)
                af[i] = *reinterpret_cast<const bf16x8*>(
                    &Als[cur][swz(wm + i * 16 + lrow, sub * 4 + lhi)]);
#pragma unroll
            for (int j = 0; j < 4; j++)
                bg[j] = *reinterpret_cast<const bf16x8*>(
                    &Bls[cur][swz(wn + j * 16 + lrow, sub * 4 + lhi)]);
#pragma unroll
            for (int i = 0; i < 2; i++)
#pragma unroll
                for (int j = 0; j < 4; j++)
                    acc[i][j] = __builtin_amdgcn_mfma_f32_16x16x32_bf16(af[i], bg[j], acc[i][j], 0, 0, 0);
        }
        if (t + 1 < T) STORET(cur ^ 1);
        __syncthreads();
        cur ^= 1;
    }
#undef LOADT
#undef STORET

#pragma unroll
    for (int i = 0; i < 2; i++) {
#pragma unroll
        for (int j = 0; j < 4; j++) {
            int n = n0 + wn + j * 16 + lrow;
            float bi = jb.bias[n];
#pragma unroll
            for (int q = 0; q < 4; q++) {
                int m = m0 + wm + i * 16 + lhi * 4 + q;
                if (m < jb.M) {
                    float val = acc[i][j][q] + bi;
                    if (jb.rowmask) val = (jb.rowmask[m] != 0.f) ? val : 0.f;
                    if (jb.C)   jb.C[(size_t)m * jb.ldc + jb.coff + n] = val;
                    if (jb.Cbf) jb.Cbf[(size_t)m * jb.ldc + jb.coff + n] = f2bf(val);
                }
            }
        }
    }
}

// ---- 4. attention: scores + softmax + c-dots fused; block=(which,b,r) ----
__global__ __launch_bounds__(512) void k_score(const u16* __restrict__ tokpB,
        const float* __restrict__ relpf, const float* __restrict__ relpb,
        const float* __restrict__ hgpf, const float* __restrict__ hgpb,
        const float* __restrict__ V_w, const float* __restrict__ V_b,
        const float* __restrict__ dd,
        float* __restrict__ c4, float* __restrict__ c5,
        float* __restrict__ c6, float* __restrict__ c7)
{
    constexpr float C = 2.8853900817779268f;   // 2*log2(e)
    int idx = blockIdx.x;            // 512
    int which = idx >> 8, b = (idx >> 6) & 3, r = idx & 63;
    int tid = threadIdx.x;
    int wid = tid >> 6, lane = tid & 63;
    int h0 = lane * 12;
    const float* relp = (which ? relpb : relpf) + (size_t)r * kH + h0;
    const float* hgp  = (which ? hgpb : hgpf) + (size_t)b * kH + h0;
    const float* vw   = V_w + h0;

    __shared__ float sc[kL];
    __shared__ float red2[2][8];

    float av2[12], w2[12], wsum = 0.f;
#pragma unroll
    for (int j = 0; j < 12; j++) {
        av2[j] = C * (relp[j] + hgp[j]);
        float wv = vw[j];
        w2[j] = -2.f * wv;
        wsum += wv;
    }
    float vb = V_b[0];
    const u16* base = tokpB + ((size_t)which * (kB * kL) + b * kL) * kH + h0;

    int l0 = wid * 32;
    bf16x4 t0 = *reinterpret_cast<const bf16x4*>(base + (size_t)l0 * kH);
    bf16x4 t1 = *reinterpret_cast<const bf16x4*>(base + (size_t)l0 * kH + 4);
    bf16x4 t2 = *reinterpret_cast<const bf16x4*>(base + (size_t)l0 * kH + 8);
    for (int l = l0; l < l0 + 32; l++) {
        bf16x4 n0, n1, n2;
        if (l + 1 < l0 + 32) {
            const u16* nrow = base + (size_t)(l + 1) * kH;
            n0 = *reinterpret_cast<const bf16x4*>(nrow);
            n1 = *reinterpret_cast<const bf16x4*>(nrow + 4);
            n2 = *reinterpret_cast<const bf16x4*>(nrow + 8);
        }
        float acc = wsum;
#pragma unroll
        for (int j = 0; j < 4; j++) {
            float e0 = fast_exp2(fmaf(bf2f((u16)t0[j]), C, av2[j]));
            acc = fmaf(w2[j], fast_rcp(e0 + 1.f), acc);
            float e1 = fast_exp2(fmaf(bf2f((u16)t1[j]), C, av2[4 + j]));
            acc = fmaf(w2[4 + j], fast_rcp(e1 + 1.f), acc);
            float e2 = fast_exp2(fmaf(bf2f((u16)t2[j]), C, av2[8 + j]));
            acc = fmaf(w2[8 + j], fast_rcp(e2 + 1.f), acc);
        }
#pragma unroll
        for (int off = 32; off; off >>= 1) acc += __shfl_xor(acc, off, 64);
        if (lane == 0) sc[l] = acc + vb;
        t0 = n0; t1 = n1; t2 = n2;
    }
    __syncthreads();

    // softmax over sc[0..255] + c-dots (A never materialized)
    int l = tid & 255;
    bool act = tid < 256;
    float x = act ? sc[l] : -3.4e38f;
    float m = x;
#pragma unroll
    for (int off = 32; off; off >>= 1) m = fmaxf(m, __shfl_xor(m, off, 64));
    if (lane == 0) red2[0][wid] = m;
    __syncthreads();
    m = fmaxf(fmaxf(red2[0][0], red2[0][1]), fmaxf(red2[0][2], red2[0][3]));
    float p = act ? __expf(x - m) : 0.f;
    float s = p;
#pragma unroll
    for (int off = 32; off; off >>= 1) s += __shfl_xor(s, off, 64);
    __syncthreads();
    if (lane == 0) red2[0][wid] = s;
    __syncthreads();
    s = red2[0][0] + red2[0][1] + red2[0][2] + red2[0][3];
    float a = p / s;
    const float* dA = dd + (size_t)(which ? 2 : 0) * 1024 + b * 256;
    const float* dB = dd + (size_t)(which ? 3 : 1) * 1024 + b * 256;
    float q0 = act ? a * dA[l] : 0.f;
    float q1 = act ? a * dB[l] : 0.f;
#pragma unroll
    for (int off = 32; off; off >>= 1) {
        q0 += __shfl_xor(q0, off, 64);
        q1 += __shfl_xor(q1, off, 64);
    }
    __syncthreads();
    if (lane == 0) { red2[0][wid] = q0; red2[1][wid] = q1; }
    __syncthreads();
    if (tid == 0) {
        float r0 = red2[0][0] + red2[0][1] + red2[0][2] + red2[0][3];
        float r1 = red2[1][0] + red2[1][1] + red2[1][2] + red2[1][3];
        if (which) { c6[b * kR + r] = r0; c7[b * kR + r] = r1; }
        else       { c4[b * kR + r] = r0; c5[b * kR + r] = r1; }
    }
}

// ---- 5. t vectors via GEMV decomposition ----
__global__ __launch_bounds__(256) void k_t(const float* __restrict__ embs,
        const u16* __restrict__ fpadB, const u16* __restrict__ bpadB,
        const float* __restrict__ uA, const float* __restrict__ uB,
        const float* __restrict__ cc,
        const float* __restrict__ fmask, const float* __restrict__ bmask,
        float* __restrict__ t4, float* __restrict__ t5,
        float* __restrict__ t6, float* __restrict__ t7)
{
    int t = blockIdx.x;               // 1024
    size_t base = (size_t)t * kH;
    float a4 = 0, a5 = 0, a6 = 0, a7 = 0, f4 = 0, f5 = 0, b6 = 0, b7 = 0;
    for (int h = threadIdx.x; h < kH; h += 256) {
        float e = embs[base + h];
        a4 += e * uB[h];
        a5 += e * uB[kH + h];
        a6 += e * uB[2 * kH + h];
        a7 += e * uB[3 * kH + h];
        float fp = bf2f(fpadB[base + h]);
        f4 += fp * uA[h];
        f5 += fp * uA[kH + h];
        float bp = bf2f(bpadB[base + h]);
        b6 += bp * uA[2 * kH + h];
        b7 += bp * uA[3 * kH + h];
    }
#pragma unroll
    for (int off = 32; off; off >>= 1) {
        a4 += __shfl_down(a4, off, 64);
        a5 += __shfl_down(a5, off, 64);
        a6 += __shfl_down(a6, off, 64);
        a7 += __shfl_down(a7, off, 64);
        f4 += __shfl_down(f4, off, 64);
        f5 += __shfl_down(f5, off, 64);
        b6 += __shfl_down(b6, off, 64);
        b7 += __shfl_down(b7, off, 64);
    }
    __shared__ float red[8][4];
    int wid = threadIdx.x >> 6;
    if ((threadIdx.x & 63) == 0) {
        red[0][wid] = a4; red[1][wid] = a5; red[2][wid] = a6; red[3][wid] = a7;
        red[4][wid] = f4; red[5][wid] = f5; red[6][wid] = b6; red[7][wid] = b7;
    }
    __syncthreads();
    if (threadIdx.x == 0) {
        float ra4 = red[0][0] + red[0][1] + red[0][2] + red[0][3];
        float ra5 = red[1][0] + red[1][1] + red[1][2] + red[1][3];
        float ra6 = red[2][0] + red[2][1] + red[2][2] + red[2][3];
        float ra7 = red[3][0] + red[3][1] + red[3][2] + red[3][3];
        float rf4 = red[4][0] + red[4][1] + red[4][2] + red[4][3];
        float rf5 = red[5][0] + red[5][1] + red[5][2] + red[5][3];
        float rb6 = red[6][0] + red[6][1] + red[6][2] + red[6][3];
        float rb7 = red[7][0] + red[7][1] + red[7][2] + red[7][3];
        bool mf = fmask[t] != 0.f, mb = bmask[t] != 0.f;
        // SELECT: masked pad rows may hold stale/poison bits -> never multiply
        t4[t] = (mf ? (rf4 + cc[0]) : 0.f) + ra4 + cc[4];
        t5[t] = (mf ? (rf5 + cc[1]) : 0.f) + ra5 + cc[5];
        t6[t] = (mb ? (rb6 + cc[2]) : 0.f) + ra6 + cc[6];
        t7[t] = (mb ? (rb7 + cc[3]) : 0.f) + ra7 + cc[7];
    }
}

// ---- 6. broadcast-add final pair logits ----
__global__ __launch_bounds__(64) void k_final(const float* __restrict__ t4,
        const float* __restrict__ t5, const float* __restrict__ t6,
        const float* __restrict__ t7, const float* __restrict__ c4,
        const float* __restrict__ c5, const float* __restrict__ c6,
        const float* __restrict__ c7, const float* __restrict__ fc_b,
        float* __restrict__ out)
{
    int which = blockIdx.x >> 10;
    int t = blockIdx.x & 1023;
    int b = t >> 8;
    int r = threadIdx.x;
    if (!which) {
        out[OFF_FOS + (size_t)t * kR + r] = t4[t] + c4[b * kR + r] + fc_b[4];
        out[OFF_FOE + (size_t)t * kR + r] = t5[t] + c5[b * kR + r] + fc_b[5];
    } else {
        out[OFF_BSS + (size_t)t * kR + r] = t6[t] + c6[b * kR + r] + fc_b[6];
        out[OFF_BSE + (size_t)t * kR + r] = t7[t] + c7[b * kR + r] + fc_b[7];
    }
}

extern "C" void kernel_launch(void* const* d_in, const int* in_sizes, int n_in,
                              void* d_out, int out_size, void* d_ws, size_t ws_size,
                              hipStream_t stream)
{
    const float* embs       = (const float*)d_in[0];
    const float* h_gs       = (const float*)d_in[1];
    const float* rel_embs   = (const float*)d_in[2];
    const float* rel_transe = (const float*)d_in[3];
    const float* fc_w       = (const float*)d_in[4];
    const float* fc_b       = (const float*)d_in[5];
    const float* Wm         = (const float*)d_in[6];
    const float* Wb         = (const float*)d_in[7];
    const float* V_w        = (const float*)d_in[8];
    const float* V_b        = (const float*)d_in[9];
    const float* rproj_w    = (const float*)d_in[10];
    const float* rproj_b    = (const float*)d_in[11];
    float* out = (float*)d_out;
    float* ws  = (float*)d_ws;

    u16* WtAll   = (u16*)(ws + WS_WTALL);
    u16* rprojT  = (u16*)(ws + WS_RPROJT);
    u16* embsB   = (u16*)(ws + WS_EMBSB);
    u16* relembB = (u16*)(ws + WS_RELEMBB);
    u16* hgsB    = (u16*)(ws + WS_HGSB);
    u16* rtransB = (u16*)(ws + WS_RTRANSB);
    u16* fpadB   = (u16*)(ws + WS_FPADB);
    u16* bpadB   = (u16*)(ws + WS_BPADB);
    u16* brelB   = (u16*)(ws + WS_BRELB);
    u16* tokpB   = (u16*)(ws + WS_TOKPB);
    float* relpf = ws + WS_RELPF;
    float* relpb = ws + WS_RELPB;
    float* hgpf  = ws + WS_HGPF;
    float* hgpb  = ws + WS_HGPB;
    float* dd    = ws + WS_DD;
    float* uA    = ws + WS_UA;
    float* uB    = ws + WS_UB;
    float* cc    = ws + WS_CC;
    float* fmask = ws + WS_FMASK;
    float* bmask = ws + WS_BMASK;
    float* t4 = ws + WS_T4; float* t5 = ws + WS_T5;
    float* t6 = ws + WS_T6; float* t7 = ws + WS_T7;
    float* c4 = ws + WS_C4; float* c5 = ws + WS_C5;
    float* c6 = ws + WS_C6; float* c7 = ws + WS_C7;
    int* jbuf     = (int*)(ws + WS_AUX);
    int* rankbuf  = jbuf + 2 * kB * kL;
    int* validbuf = rankbuf + 2 * kB * kL;

    // 1. mega-prep (everything depending only on inputs)
    k_prep_all<<<3588, 256, 0, stream>>>(embs, rel_embs, h_gs, rel_transe,
        fc_w, fc_b, Wm, Wb, rproj_w,
        out, embsB, relembB, hgsB, rtransB, WtAll, rprojT, uA, uB, cc, dd);

    // 2. span extraction: meta (8 blocks) then means (2048 blocks, parallel)
    k_extract_meta<<<2 * kB, 256, 0, stream>>>(out, jbuf, rankbuf, validbuf, fmask, bmask);
    k_span_mean<<<2 * kB * kL, 256, 0, stream>>>(embs, jbuf, rankbuf, validbuf, fpadB, bpadB);

    // 3. t vectors
    k_t<<<kB * kL, 256, 0, stream>>>(embs, fpadB, bpadB, uA, uB, cc, fmask, bmask,
                                     t4, t5, t6, t7);

    // 4. gemmA: relpf, hgpf, hgpb, brel, tokp x2
    {
        GemmBatch bt;
        bt.j[0] = { relembB, WtAll + 2 * HH, Wb + 2 * kH, relpf, nullptr, nullptr, kR, kH, kH, 0 };
        bt.j[1] = { hgsB,    WtAll + 3 * HH, Wb + 3 * kH, hgpf,  nullptr, nullptr, kB, kH, kH, 0 };
        bt.j[2] = { hgsB,    WtAll + 6 * HH, Wb + 6 * kH, hgpb,  nullptr, nullptr, kB, kH, kH, 0 };
        bt.j[3] = { rtransB, rprojT,         rproj_b,     nullptr, brelB, nullptr, kR, 128, kH, 0 };
        bt.j[4] = { embsB,   WtAll + 4 * HH, Wb + 4 * kH, nullptr, tokpB,            nullptr, kB * kL, kH, kH, 0 };
        bt.j[5] = { embsB,   WtAll + 7 * HH, Wb + 7 * kH, nullptr, tokpB + (size_t)kB * kL * kH, nullptr, kB * kL, kH, kH, 0 };
        k_gemm_mfma<<<dim3(16, 6, 6), 256, 0, stream>>>(bt);
    }
    // 5. gemmB: relpb = brel @ Wm5
    {
        GemmBatch bt;
        bt.j[0] = { brelB, WtAll + 5 * HH, Wb + 5 * kH, relpb, nullptr, nullptr, kR, kH, kH, 0 };
        for (int z = 1; z < 6; z++) bt.j[z] = bt.j[0];
        k_gemm_mfma<<<dim3(1, 6, 1), 256, 0, stream>>>(bt);
    }

    // 6. fused scores + softmax + c-dots
    k_score<<<512, 512, 0, stream>>>(tokpB, relpf, relpb, hgpf, hgpb, V_w, V_b,
                                     dd, c4, c5, c6, c7);

    // 7. final broadcast-add
    k_final<<<2 * kB * kL, 64, 0, stream>>>(t4, t5, t6, t7, c4, c5, c6, c7, fc_b, out);
}

// Round 11
// 92.554 us; speedup vs baseline: 3.2555x; 1.1002x over previous
//
#include <hip/hip_runtime.h>
#include <cstddef>

using u16 = unsigned short;
typedef __attribute__((ext_vector_type(8))) short bf16x8;
typedef __attribute__((ext_vector_type(4))) short bf16x4;
typedef __attribute__((ext_vector_type(4))) float f32x4;

constexpr int kB = 4, kL = 256, kR = 64, kH = 768, kTE = 100;
constexpr size_t HH = (size_t)kH * kH;

// ---- output offsets (floats) in return order ----
constexpr size_t OFF_FSS = 0;
constexpr size_t OFF_FSE = OFF_FSS + kB * kL;
constexpr size_t OFF_FOS = OFF_FSE + kB * kL;
constexpr size_t OFF_FOE = OFF_FOS + (size_t)kB * kL * kR;
constexpr size_t OFF_BOS = OFF_FOE + (size_t)kB * kL * kR;
constexpr size_t OFF_BOE = OFF_BOS + kB * kL;
constexpr size_t OFF_BSS = OFF_BOE + kB * kL;
constexpr size_t OFF_BSE = OFF_BSS + (size_t)kB * kL * kR;

// ---- workspace layout (float units), no aliasing ----
constexpr size_t WS_WTALL   = 0;                                   // 10xHH u16 (2..7 used)
constexpr size_t WS_EMBSB   = WS_WTALL   + 10 * HH / 2;            // 1024x768 u16
constexpr size_t WS_RELEMBB = WS_EMBSB   + (1024 * 768) / 2;       // 64x768 u16
constexpr size_t WS_HGSB    = WS_RELEMBB + (64 * 768) / 2;         // 4x768 u16
constexpr size_t WS_FPADB   = WS_HGSB    + (4 * 768) / 2;          // 1024x768 u16
constexpr size_t WS_BPADB   = WS_FPADB   + (1024 * 768) / 2;       // 1024x768 u16
constexpr size_t WS_BRELB   = WS_BPADB   + (1024 * 768) / 2;       // 64x768 u16
constexpr size_t WS_TOKPB   = WS_BRELB   + (64 * 768) / 2;         // 2x1024x768 u16
constexpr size_t WS_RELPF   = WS_TOKPB   + (2 * 1024 * 768) / 2;   // 64x768 f32
constexpr size_t WS_RELPB   = WS_RELPF   + 64 * 768;
constexpr size_t WS_HGPF    = WS_RELPB   + 64 * 768;               // 4x768 f32
constexpr size_t WS_HGPB    = WS_HGPF    + 4 * 768;
constexpr size_t WS_DD      = WS_HGPB    + 4 * 768;                // 4x1024 f32 (d4..d7)
constexpr size_t WS_UA      = WS_DD      + 4 * 1024;               // 4x768 f32
constexpr size_t WS_UB      = WS_UA      + 4 * 768;                // 4x768 f32
constexpr size_t WS_CC      = WS_UB      + 4 * 768;                // 8 f32
constexpr size_t WS_FMASK   = WS_CC      + 8;
constexpr size_t WS_BMASK   = WS_FMASK   + 1024;
constexpr size_t WS_C4      = WS_BMASK   + 1024;
constexpr size_t WS_C5      = WS_C4 + 256;
constexpr size_t WS_C6      = WS_C5 + 256;
constexpr size_t WS_C7      = WS_C6 + 256;
constexpr size_t WS_AUX     = WS_C7 + 256;      // int region: jbuf/rankbuf/validbuf

__device__ inline float fast_rcp(float x) {
#if __has_builtin(__builtin_amdgcn_rcpf)
    return __builtin_amdgcn_rcpf(x);
#else
    return 1.f / x;
#endif
}
__device__ inline float fast_exp2(float x) {
#if __has_builtin(__builtin_amdgcn_exp2f)
    return __builtin_amdgcn_exp2f(x);
#else
    return __exp2f(x);
#endif
}
__device__ inline u16 f2bf(float x) {   // RNE
    union { float f; unsigned u; } v; v.f = x;
    unsigned r = v.u + 0x7FFFu + ((v.u >> 16) & 1u);
    return (u16)(r >> 16);
}
__device__ inline float bf2f(u16 x) {
    union { unsigned u; float f; } v; v.u = ((unsigned)x) << 16;
    return v.f;
}

// ---- 1. mega-prep ----
// [0,1024) logits+embsB+dd | [1024,1888) Wm2..7 transpose | [1888,3424) gemv
// [3424,3488) relemb cast | [3488,3492) hgs cast | [3492,3556) brel fp32 GEMV | [3556,3564) cc
__global__ __launch_bounds__(256) void k_prep_all(
        const float* __restrict__ embs, const float* __restrict__ rel_embs,
        const float* __restrict__ h_gs, const float* __restrict__ rel_transe,
        const float* __restrict__ fc_w, const float* __restrict__ fc_b,
        const float* __restrict__ Wm, const float* __restrict__ Wb,
        const float* __restrict__ rproj_w, const float* __restrict__ rproj_b,
        float* __restrict__ out, u16* __restrict__ embsB,
        u16* __restrict__ relembB, u16* __restrict__ hgsB, u16* __restrict__ brelB,
        u16* __restrict__ WtAll,
        float* __restrict__ uA, float* __restrict__ uB, float* __restrict__ cc,
        float* __restrict__ dd)
{
    __shared__ float sh[64 * 65];
    int bx = blockIdx.x, t = threadIdx.x;
    if (bx < 1024) {
        // per-token: embsB cast + 8 dots (4 exact logits, 4 d-vectors)
        int tok = bx;
        const float* e = embs + (size_t)tok * kH;
        float s[8] = {0, 0, 0, 0, 0, 0, 0, 0};
        for (int h = t; h < kH; h += 256) {
            float x = e[h];
            embsB[(size_t)tok * kH + h] = f2bf(x);
#pragma unroll
            for (int j = 0; j < 8; j++) s[j] += x * fc_w[j * kH + h];
        }
#pragma unroll
        for (int off = 32; off; off >>= 1)
#pragma unroll
            for (int j = 0; j < 8; j++) s[j] += __shfl_down(s[j], off, 64);
        float(*red)[4] = (float(*)[4])sh;
        int wid = t >> 6;
        if ((t & 63) == 0) {
#pragma unroll
            for (int j = 0; j < 8; j++) red[j][wid] = s[j];
        }
        __syncthreads();
        if (t == 0) {
            float r[8];
#pragma unroll
            for (int j = 0; j < 8; j++) r[j] = red[j][0] + red[j][1] + red[j][2] + red[j][3];
            out[OFF_FSS + tok] = r[0] + fc_b[0];
            out[OFF_FSE + tok] = r[1] + fc_b[1];
            out[OFF_BOS + tok] = r[2] + fc_b[2];
            out[OFF_BOE + tok] = r[3] + fc_b[3];
            dd[0 * 1024 + tok] = r[4];
            dd[1 * 1024 + tok] = r[5];
            dd[2 * 1024 + tok] = r[6];
            dd[3 * 1024 + tok] = r[7];
        }
    } else if (bx < 1888) {
        // weight transpose Wm2..7: Wt[n][k] = W[k][n]
        int px = bx - 1024;
        int mi = 2 + px / 144, tile = px % 144;
        int kt = (tile / 12) * 64, nt = (tile % 12) * 64;
        const float* src = Wm + (size_t)mi * HH;
        u16* dst = WtAll + (size_t)mi * HH;
        float(*tl)[65] = (float(*)[65])sh;
        int r = t >> 2, cq = (t & 3) * 16;
        int row = kt + r;
#pragma unroll
        for (int q = 0; q < 4; q++) {
            float4 v = *(const float4*)(src + (size_t)row * kH + nt + cq + q * 4);
            tl[r][cq + q * 4 + 0] = v.x;
            tl[r][cq + q * 4 + 1] = v.y;
            tl[r][cq + q * 4 + 2] = v.z;
            tl[r][cq + q * 4 + 3] = v.w;
        }
        __syncthreads();
        u16* drow = dst + (size_t)(nt + r) * kH + kt + cq;
#pragma unroll
        for (int j = 0; j < 16; j++) drow[j] = f2bf(tl[cq + j][r]);
    } else if (bx < 3424) {
        // GEMVs: uA[j]=Wm{0,0,1,1}@w{4..7}; uB[j]=Wm{8,8,9,9}@w{4..7}+w
        int gx = bx - 1888;
        int j = gx / 192;
        int wid = t >> 6, lane = t & 63;
        int row = (gx % 192) * 4 + wid;
        const int wmI[8] = {0, 0, 1, 1, 8, 8, 9, 9};
        const int fcI[8] = {4, 5, 6, 7, 4, 5, 6, 7};
        const float* W = Wm + (size_t)wmI[j] * HH + (size_t)row * kH;
        const float* w = fc_w + (size_t)fcI[j] * kH;
        float s = 0.f;
        for (int c = lane; c < kH; c += 64) s += W[c] * w[c];
#pragma unroll
        for (int off = 32; off; off >>= 1) s += __shfl_xor(s, off, 64);
        if (lane == 0) {
            if (j < 4) uA[j * kH + row] = s;
            else       uB[(j - 4) * kH + row] = s + w[row];
        }
    } else if (bx < 3488) {
        int r = bx - 3424;
        for (int h = t; h < kH; h += 256) relembB[r * kH + h] = f2bf(rel_embs[r * kH + h]);
    } else if (bx < 3492) {
        int r = bx - 3488;
        for (int h = t; h < kH; h += 256) hgsB[r * kH + h] = f2bf(h_gs[r * kH + h]);
    } else if (bx < 3556) {
        // brel row r: fp32 GEMV rel_transe[r] @ rproj_w + rproj_b -> bf16
        int r = bx - 3492;
        if (t < kTE) sh[t] = rel_transe[r * kTE + t];
        __syncthreads();
        float a0 = rproj_b[t], a1 = rproj_b[t + 256], a2 = rproj_b[t + 512];
        for (int k = 0; k < kTE; k++) {
            float rv = sh[k];
            const float* wr = rproj_w + (size_t)k * kH;
            a0 = fmaf(rv, wr[t], a0);
            a1 = fmaf(rv, wr[t + 256], a1);
            a2 = fmaf(rv, wr[t + 512], a2);
        }
        brelB[r * kH + t]       = f2bf(a0);
        brelB[r * kH + t + 256] = f2bf(a1);
        brelB[r * kH + t + 512] = f2bf(a2);
    } else {
        // cc[j] = Wb[{0,0,1,1,8,8,9,9}[j]] . fc_w[{4,5,6,7,...}[j]]
        int j = bx - 3556;
        const int wbI[8] = {0, 0, 1, 1, 8, 8, 9, 9};
        const int fcI[8] = {4, 5, 6, 7, 4, 5, 6, 7};
        const float* wb = Wb + (size_t)wbI[j] * kH;
        const float* w  = fc_w + (size_t)fcI[j] * kH;
        float s = 0.f;
        for (int h = t; h < kH; h += 256) s += wb[h] * w[h];
#pragma unroll
        for (int off = 32; off; off >>= 1) s += __shfl_down(s, off, 64);
        int wid = t >> 6;
        if ((t & 63) == 0) sh[wid] = s;
        __syncthreads();
        if (t == 0) cc[j] = sh[0] + sh[1] + sh[2] + sh[3];
    }
}

// ---- 2a. span extraction metadata (8 blocks, LDS scans) ----
__global__ __launch_bounds__(256) void k_extract_meta(const float* __restrict__ out,
        int* __restrict__ jbuf, int* __restrict__ rankbuf, int* __restrict__ validbuf,
        float* __restrict__ fmask, float* __restrict__ bmask)
{
    int which = blockIdx.x >> 2;
    int b = blockIdx.x & 3;
    int i = threadIdx.x;
    const float* slog = out + (which ? OFF_BOS : OFF_FSS) + (size_t)b * kL;
    const float* elog = out + (which ? OFF_BOE : OFF_FSE) + (size_t)b * kL;
    float sv = slog[i], ev = elog[i];
    bool st = (1.f / (1.f + __expf(-sv)) > 0.5f);
    bool en = (1.f / (1.f + __expf(-ev)) > 0.5f);

    __shared__ int sm[kL];
    __shared__ int ps[kL];
    sm[i] = en ? i : kL;
    __syncthreads();
    for (int step = 1; step < kL; step <<= 1) {  // suffix min
        int v = (i + step < kL) ? sm[i + step] : kL;
        __syncthreads();
        sm[i] = min(sm[i], v);
        __syncthreads();
    }
    int next_end = sm[i];
    int validi = (st && next_end < kL) ? 1 : 0;
    ps[i] = validi;
    __syncthreads();
    for (int step = 1; step < kL; step <<= 1) {  // inclusive prefix sum
        int v = (i >= step) ? ps[i - step] : 0;
        __syncthreads();
        ps[i] += v;
        __syncthreads();
    }
    int rank = ps[i] - 1;
    int num = ps[kL - 1];
    int gbase = (which * kB + b) * kL + i;
    jbuf[gbase] = min(next_end, kL - 1);
    rankbuf[gbase] = rank;
    validbuf[gbase] = validi;
    (which ? bmask : fmask)[b * kL + i] = (i < num) ? 1.f : 0.f;
}

// ---- 2b. span means packed by rank (2048 blocks, parallel) ----
__global__ __launch_bounds__(256) void k_span_mean(const float* __restrict__ embs,
        const int* __restrict__ jbuf, const int* __restrict__ rankbuf,
        const int* __restrict__ validbuf, u16* __restrict__ fpadB, u16* __restrict__ bpadB)
{
    int idx = blockIdx.x;
    int which = idx >> 10;
    int b = (idx >> 8) & 3;
    int i = idx & 255;
    int gbase = (which * kB + b) * kL + i;
    if (!validbuf[gbase]) return;
    int j = jbuf[gbase];
    int rk = rankbuf[gbase];
    int len = j - i + 1;
    float inv = 1.f / (float)len;
    u16* pad = (which ? bpadB : fpadB) + ((size_t)(b * kL + rk)) * kH;
    const float* e = embs + ((size_t)(b * kL + i)) * kH;
    for (int h = threadIdx.x; h < kH; h += 256) {
        float s = 0.f;
        for (int row = 0; row < len; row++) s += e[(size_t)row * kH + h];
        pad[h] = f2bf(s * inv);
    }
}

// ---- 3. batched MFMA GEMM, 64x64 tile, BK=64, dbuf + reg-prefetch ----
// LDS 32KB -> up to 5 blocks/CU; small-GEMM latency regime favors max TLP.
struct GemmJob {
    const u16* A; const u16* Wt; const float* bias;
    float* C; u16* Cbf; const float* rowmask;
    int M; int K; int ldc; int coff;
};
struct GemmBatch { GemmJob j[6]; };

__device__ inline int swz(int row, int slot) {   // short-index into [row][64] layout
    return row * 64 + ((slot ^ (row & 7)) << 3);
}

__global__ __launch_bounds__(256) void k_gemm_mfma(GemmBatch batch)
{
    GemmJob jb = batch.j[blockIdx.z];
    if (blockIdx.x * 64 >= jb.M) return;
    __shared__ short Als[2][64 * 64];      // 16 KB
    __shared__ short Bls[2][64 * 64];      // 16 KB
    int tid = threadIdx.x;
    int m0 = blockIdx.x * 64;
    int n0 = blockIdx.y * 64;
    int w = tid >> 6, lane = tid & 63;
    int wm = (w >> 1) * 32, wn = (w & 1) * 32;   // 2M x 2N waves, each 32x32
    int lrow = lane & 15, lhi = lane >> 4;
    int srow = tid >> 2, sc0 = tid & 3;          // chunks sc0 and sc0+4
    int K = jb.K;
    int T = K >> 6;

    f32x4 zero4 = {0.f, 0.f, 0.f, 0.f};
    f32x4 acc[2][2];
#pragma unroll
    for (int i = 0; i < 2; i++)
#pragma unroll
        for (int j = 0; j < 2; j++) acc[i][j] = zero4;

    bf16x8 pa[2], pb[2];

#define LOADT(k0)                                                                 \
    {                                                                             \
        _Pragma("unroll")                                                         \
        for (int q = 0; q < 2; q++) {                                             \
            bf16x8 va;                                                            \
            _Pragma("unroll") for (int z = 0; z < 8; z++) va[z] = 0;              \
            if (m0 + srow < jb.M)                                                 \
                va = *reinterpret_cast<const bf16x8*>(                            \
                    jb.A + (size_t)(m0 + srow) * K + (k0) + (sc0 + q * 4) * 8);   \
            pa[q] = va;                                                           \
            pb[q] = *reinterpret_cast<const bf16x8*>(                             \
                jb.Wt + (size_t)(n0 + srow) * K + (k0) + (sc0 + q * 4) * 8);      \
        }                                                                         \
    }
#define STORET(buf)                                                               \
    {                                                                             \
        _Pragma("unroll")                                                         \
        for (int q = 0; q < 2; q++) {                                             \
            *reinterpret_cast<bf16x8*>(&Als[buf][swz(srow, sc0 + q * 4)]) = pa[q];\
            *reinterpret_cast<bf16x8*>(&Bls[buf][swz(srow, sc0 + q * 4)]) = pb[q];\
        }                                                                         \
    }

    LOADT(0);
    STORET(0);
    __syncthreads();
    int cur = 0;
    for (int t = 0; t < T; t++) {
        if (t + 1 < T) LOADT((t + 1) << 6);
#pragma unroll
        for (int sub = 0; sub < 2; sub++) {
            bf16x8 af[2], bg[2];
#pragma unroll
            for (int i = 0; i < 2; i++) {
                af[i] = *reinterpret_cast<const bf16x8*>(
                    &Als[cur][swz(wm + i * 16 + lrow, sub * 4 + lhi)]);
                bg[i] = *reinterpret_cast<const bf16x8*>(
                    &Bls[cur][swz(wn + i * 16 + lrow, sub * 4 + lhi)]);
            }
#pragma unroll
            for (int i = 0; i < 2; i++)
#pragma unroll
                for (int j = 0; j < 2; j++)
                    acc[i][j] = __builtin_amdgcn_mfma_f32_16x16x32_bf16(af[i], bg[j], acc[i][j], 0, 0, 0);
        }
        if (t + 1 < T) STORET(cur ^ 1);
        __syncthreads();
        cur ^= 1;
    }
#undef LOADT
#undef STORET

#pragma unroll
    for (int i = 0; i < 2; i++) {
#pragma unroll
        for (int j = 0; j < 2; j++) {
            int n = n0 + wn + j * 16 + lrow;
            float bi = jb.bias[n];
#pragma unroll
            for (int q = 0; q < 4; q++) {
                int m = m0 + wm + i * 16 + lhi * 4 + q;
                if (m < jb.M) {
                    float val = acc[i][j][q] + bi;
                    if (jb.rowmask) val = (jb.rowmask[m] != 0.f) ? val : 0.f;
                    if (jb.C)   jb.C[(size_t)m * jb.ldc + jb.coff + n] = val;
                    if (jb.Cbf) jb.Cbf[(size_t)m * jb.ldc + jb.coff + n] = f2bf(val);
                }
            }
        }
    }
}

// ---- 4. attention: scores + softmax + c-dots fused; block=(which,b,r) ----
__global__ __launch_bounds__(512) void k_score(const u16* __restrict__ tokpB,
        const float* __restrict__ relpf, const float* __restrict__ relpb,
        const float* __restrict__ hgpf, const float* __restrict__ hgpb,
        const float* __restrict__ V_w, const float* __restrict__ V_b,
        const float* __restrict__ dd,
        float* __restrict__ c4, float* __restrict__ c5,
        float* __restrict__ c6, float* __restrict__ c7)
{
    constexpr float C = 2.8853900817779268f;   // 2*log2(e)
    int idx = blockIdx.x;            // 512
    int which = idx >> 8, b = (idx >> 6) & 3, r = idx & 63;
    int tid = threadIdx.x;
    int wid = tid >> 6, lane = tid & 63;
    int h0 = lane * 12;
    const float* relp = (which ? relpb : relpf) + (size_t)r * kH + h0;
    const float* hgp  = (which ? hgpb : hgpf) + (size_t)b * kH + h0;
    const float* vw   = V_w + h0;

    __shared__ float sc[kL];
    __shared__ float red2[2][8];

    float av2[12], w2[12], wsum = 0.f;
#pragma unroll
    for (int j = 0; j < 12; j++) {
        av2[j] = C * (relp[j] + hgp[j]);
        float wv = vw[j];
        w2[j] = -2.f * wv;
        wsum += wv;
    }
    float vb = V_b[0];
    const u16* base = tokpB + ((size_t)which * (kB * kL) + b * kL) * kH + h0;

    int l0 = wid * 32;
    bf16x4 t0 = *reinterpret_cast<const bf16x4*>(base + (size_t)l0 * kH);
    bf16x4 t1 = *reinterpret_cast<const bf16x4*>(base + (size_t)l0 * kH + 4);
    bf16x4 t2 = *reinterpret_cast<const bf16x4*>(base + (size_t)l0 * kH + 8);
    for (int l = l0; l < l0 + 32; l++) {
        bf16x4 n0, n1, n2;
        if (l + 1 < l0 + 32) {
            const u16* nrow = base + (size_t)(l + 1) * kH;
            n0 = *reinterpret_cast<const bf16x4*>(nrow);
            n1 = *reinterpret_cast<const bf16x4*>(nrow + 4);
            n2 = *reinterpret_cast<const bf16x4*>(nrow + 8);
        }
        float acc = wsum;
#pragma unroll
        for (int j = 0; j < 4; j++) {
            float e0 = fast_exp2(fmaf(bf2f((u16)t0[j]), C, av2[j]));
            acc = fmaf(w2[j], fast_rcp(e0 + 1.f), acc);
            float e1 = fast_exp2(fmaf(bf2f((u16)t1[j]), C, av2[4 + j]));
            acc = fmaf(w2[4 + j], fast_rcp(e1 + 1.f), acc);
            float e2 = fast_exp2(fmaf(bf2f((u16)t2[j]), C, av2[8 + j]));
            acc = fmaf(w2[8 + j], fast_rcp(e2 + 1.f), acc);
        }
#pragma unroll
        for (int off = 32; off; off >>= 1) acc += __shfl_xor(acc, off, 64);
        if (lane == 0) sc[l] = acc + vb;
        t0 = n0; t1 = n1; t2 = n2;
    }
    __syncthreads();

    // softmax over sc[0..255] + c-dots (A never materialized)
    int l = tid & 255;
    bool act = tid < 256;
    float x = act ? sc[l] : -3.4e38f;
    float m = x;
#pragma unroll
    for (int off = 32; off; off >>= 1) m = fmaxf(m, __shfl_xor(m, off, 64));
    if (lane == 0) red2[0][wid] = m;
    __syncthreads();
    m = fmaxf(fmaxf(red2[0][0], red2[0][1]), fmaxf(red2[0][2], red2[0][3]));
    float p = act ? __expf(x - m) : 0.f;
    float s = p;
#pragma unroll
    for (int off = 32; off; off >>= 1) s += __shfl_xor(s, off, 64);
    __syncthreads();
    if (lane == 0) red2[0][wid] = s;
    __syncthreads();
    s = red2[0][0] + red2[0][1] + red2[0][2] + red2[0][3];
    float a = p / s;
    const float* dA = dd + (size_t)(which ? 2 : 0) * 1024 + b * 256;
    const float* dB = dd + (size_t)(which ? 3 : 1) * 1024 + b * 256;
    float q0 = act ? a * dA[l] : 0.f;
    float q1 = act ? a * dB[l] : 0.f;
#pragma unroll
    for (int off = 32; off; off >>= 1) {
        q0 += __shfl_xor(q0, off, 64);
        q1 += __shfl_xor(q1, off, 64);
    }
    __syncthreads();
    if (lane == 0) { red2[0][wid] = q0; red2[1][wid] = q1; }
    __syncthreads();
    if (tid == 0) {
        float r0 = red2[0][0] + red2[0][1] + red2[0][2] + red2[0][3];
        float r1 = red2[1][0] + red2[1][1] + red2[1][2] + red2[1][3];
        if (which) { c6[b * kR + r] = r0; c7[b * kR + r] = r1; }
        else       { c4[b * kR + r] = r0; c5[b * kR + r] = r1; }
    }
}

// ---- 5. t vectors (GEMV decomposition) + fused final broadcast-add ----
__global__ __launch_bounds__(256) void k_t_final(const float* __restrict__ embs,
        const u16* __restrict__ fpadB, const u16* __restrict__ bpadB,
        const float* __restrict__ uA, const float* __restrict__ uB,
        const float* __restrict__ cc,
        const float* __restrict__ fmask, const float* __restrict__ bmask,
        const float* __restrict__ c4, const float* __restrict__ c5,
        const float* __restrict__ c6, const float* __restrict__ c7,
        const float* __restrict__ fc_b, float* __restrict__ out)
{
    int t = blockIdx.x;               // 1024
    int b = t >> 8;
    size_t base = (size_t)t * kH;
    float a4 = 0, a5 = 0, a6 = 0, a7 = 0, f4 = 0, f5 = 0, b6 = 0, b7 = 0;
    for (int h = threadIdx.x; h < kH; h += 256) {
        float e = embs[base + h];
        a4 += e * uB[h];
        a5 += e * uB[kH + h];
        a6 += e * uB[2 * kH + h];
        a7 += e * uB[3 * kH + h];
        float fp = bf2f(fpadB[base + h]);
        f4 += fp * uA[h];
        f5 += fp * uA[kH + h];
        float bp = bf2f(bpadB[base + h]);
        b6 += bp * uA[2 * kH + h];
        b7 += bp * uA[3 * kH + h];
    }
#pragma unroll
    for (int off = 32; off; off >>= 1) {
        a4 += __shfl_down(a4, off, 64);
        a5 += __shfl_down(a5, off, 64);
        a6 += __shfl_down(a6, off, 64);
        a7 += __shfl_down(a7, off, 64);
        f4 += __shfl_down(f4, off, 64);
        f5 += __shfl_down(f5, off, 64);
        b6 += __shfl_down(b6, off, 64);
        b7 += __shfl_down(b7, off, 64);
    }
    __shared__ float red[8][4];
    __shared__ float fin[4];
    int wid = threadIdx.x >> 6;
    if ((threadIdx.x & 63) == 0) {
        red[0][wid] = a4; red[1][wid] = a5; red[2][wid] = a6; red[3][wid] = a7;
        red[4][wid] = f4; red[5][wid] = f5; red[6][wid] = b6; red[7][wid] = b7;
    }
    __syncthreads();
    if (threadIdx.x == 0) {
        float ra4 = red[0][0] + red[0][1] + red[0][2] + red[0][3];
        float ra5 = red[1][0] + red[1][1] + red[1][2] + red[1][3];
        float ra6 = red[2][0] + red[2][1] + red[2][2] + red[2][3];
        float ra7 = red[3][0] + red[3][1] + red[3][2] + red[3][3];
        float rf4 = red[4][0] + red[4][1] + red[4][2] + red[4][3];
        float rf5 = red[5][0] + red[5][1] + red[5][2] + red[5][3];
        float rb6 = red[6][0] + red[6][1] + red[6][2] + red[6][3];
        float rb7 = red[7][0] + red[7][1] + red[7][2] + red[7][3];
        bool mf = fmask[t] != 0.f, mb = bmask[t] != 0.f;
        // SELECT: masked pad rows may hold stale/poison bits -> never multiply
        fin[0] = (mf ? (rf4 + cc[0]) : 0.f) + ra4 + cc[4];
        fin[1] = (mf ? (rf5 + cc[1]) : 0.f) + ra5 + cc[5];
        fin[2] = (mb ? (rb6 + cc[2]) : 0.f) + ra6 + cc[6];
        fin[3] = (mb ? (rb7 + cc[3]) : 0.f) + ra7 + cc[7];
    }
    __syncthreads();
    // fused final: each of 256 threads writes one output value (coalesced 64-wide)
    int row = threadIdx.x >> 6, r = threadIdx.x & 63;
    const float* cp = (row == 0) ? c4 : (row == 1) ? c5 : (row == 2) ? c6 : c7;
    size_t off = (row == 0) ? OFF_FOS : (row == 1) ? OFF_FOE : (row == 2) ? OFF_BSS : OFF_BSE;
    out[off + (size_t)t * kR + r] = fin[row] + cp[b * kR + r] + fc_b[4 + row];
}

extern "C" void kernel_launch(void* const* d_in, const int* in_sizes, int n_in,
                              void* d_out, int out_size, void* d_ws, size_t ws_size,
                              hipStream_t stream)
{
    const float* embs       = (const float*)d_in[0];
    const float* h_gs       = (const float*)d_in[1];
    const float* rel_embs   = (const float*)d_in[2];
    const float* rel_transe = (const float*)d_in[3];
    const float* fc_w       = (const float*)d_in[4];
    const float* fc_b       = (const float*)d_in[5];
    const float* Wm         = (const float*)d_in[6];
    const float* Wb         = (const float*)d_in[7];
    const float* V_w        = (const float*)d_in[8];
    const float* V_b        = (const float*)d_in[9];
    const float* rproj_w    = (const float*)d_in[10];
    const float* rproj_b    = (const float*)d_in[11];
    float* out = (float*)d_out;
    float* ws  = (float*)d_ws;

    u16* WtAll   = (u16*)(ws + WS_WTALL);
    u16* embsB   = (u16*)(ws + WS_EMBSB);
    u16* relembB = (u16*)(ws + WS_RELEMBB);
    u16* hgsB    = (u16*)(ws + WS_HGSB);
    u16* fpadB   = (u16*)(ws + WS_FPADB);
    u16* bpadB   = (u16*)(ws + WS_BPADB);
    u16* brelB   = (u16*)(ws + WS_BRELB);
    u16* tokpB   = (u16*)(ws + WS_TOKPB);
    float* relpf = ws + WS_RELPF;
    float* relpb = ws + WS_RELPB;
    float* hgpf  = ws + WS_HGPF;
    float* hgpb  = ws + WS_HGPB;
    float* dd    = ws + WS_DD;
    float* uA    = ws + WS_UA;
    float* uB    = ws + WS_UB;
    float* cc    = ws + WS_CC;
    float* fmask = ws + WS_FMASK;
    float* bmask = ws + WS_BMASK;
    float* c4 = ws + WS_C4; float* c5 = ws + WS_C5;
    float* c6 = ws + WS_C6; float* c7 = ws + WS_C7;
    int* jbuf     = (int*)(ws + WS_AUX);
    int* rankbuf  = jbuf + 2 * kB * kL;
    int* validbuf = rankbuf + 2 * kB * kL;

    // 1. mega-prep (everything depending only on inputs, incl. brel fp32 GEMV)
    k_prep_all<<<3564, 256, 0, stream>>>(embs, rel_embs, h_gs, rel_transe,
        fc_w, fc_b, Wm, Wb, rproj_w, rproj_b,
        out, embsB, relembB, hgsB, brelB, WtAll, uA, uB, cc, dd);

    // 2. span extraction: meta (8 blocks) then means (2048 blocks, parallel)
    k_extract_meta<<<2 * kB, 256, 0, stream>>>(out, jbuf, rankbuf, validbuf, fmask, bmask);
    k_span_mean<<<2 * kB * kL, 256, 0, stream>>>(embs, jbuf, rankbuf, validbuf, fpadB, bpadB);

    // 3. gemmA: relpf, hgpf, hgpb, relpb, tokp x2 (single launch)
    {
        GemmBatch bt;
        bt.j[0] = { relembB, WtAll + 2 * HH, Wb + 2 * kH, relpf, nullptr, nullptr, kR, kH, kH, 0 };
        bt.j[1] = { hgsB,    WtAll + 3 * HH, Wb + 3 * kH, hgpf,  nullptr, nullptr, kB, kH, kH, 0 };
        bt.j[2] = { hgsB,    WtAll + 6 * HH, Wb + 6 * kH, hgpb,  nullptr, nullptr, kB, kH, kH, 0 };
        bt.j[3] = { brelB,   WtAll + 5 * HH, Wb + 5 * kH, relpb, nullptr, nullptr, kR, kH, kH, 0 };
        bt.j[4] = { embsB,   WtAll + 4 * HH, Wb + 4 * kH, nullptr, tokpB,            nullptr, kB * kL, kH, kH, 0 };
        bt.j[5] = { embsB,   WtAll + 7 * HH, Wb + 7 * kH, nullptr, tokpB + (size_t)kB * kL * kH, nullptr, kB * kL, kH, kH, 0 };
        k_gemm_mfma<<<dim3(16, 12, 6), 256, 0, stream>>>(bt);
    }

    // 4. fused scores + softmax + c-dots
    k_score<<<512, 512, 0, stream>>>(tokpB, relpf, relpb, hgpf, hgpb, V_w, V_b,
                                     dd, c4, c5, c6, c7);

    // 5. t vectors + fused final broadcast-add
    k_t_final<<<kB * kL, 256, 0, stream>>>(embs, fpadB, bpadB, uA, uB, cc, fmask, bmask,
                                           c4, c5, c6, c7, fc_b, out);
}

// Round 12
// 78.989 us; speedup vs baseline: 3.8145x; 1.1717x over previous
//
#include <hip/hip_runtime.h>
#include <cstddef>

using u16 = unsigned short;
typedef __attribute__((ext_vector_type(8))) short bf16x8;
typedef __attribute__((ext_vector_type(4))) short bf16x4;
typedef __attribute__((ext_vector_type(4))) float f32x4;

constexpr int kB = 4, kL = 256, kR = 64, kH = 768, kTE = 100;
constexpr size_t HH = (size_t)kH * kH;

// ---- output offsets (floats) in return order ----
constexpr size_t OFF_FSS = 0;
constexpr size_t OFF_FSE = OFF_FSS + kB * kL;
constexpr size_t OFF_FOS = OFF_FSE + kB * kL;
constexpr size_t OFF_FOE = OFF_FOS + (size_t)kB * kL * kR;
constexpr size_t OFF_BOS = OFF_FOE + (size_t)kB * kL * kR;
constexpr size_t OFF_BOE = OFF_BOS + kB * kL;
constexpr size_t OFF_BSS = OFF_BOE + kB * kL;
constexpr size_t OFF_BSE = OFF_BSS + (size_t)kB * kL * kR;

// ---- workspace layout (float units), no aliasing ----
constexpr size_t WS_WTALL   = 0;                                   // 10xHH u16 (2..7 used)
constexpr size_t WS_EMBSB   = WS_WTALL   + 10 * HH / 2;            // 1024x768 u16
constexpr size_t WS_RELEMBB = WS_EMBSB   + (1024 * 768) / 2;       // 64x768 u16
constexpr size_t WS_HGSB    = WS_RELEMBB + (64 * 768) / 2;         // 4x768 u16
constexpr size_t WS_FPADB   = WS_HGSB    + (4 * 768) / 2;          // 1024x768 u16
constexpr size_t WS_BPADB   = WS_FPADB   + (1024 * 768) / 2;       // 1024x768 u16
constexpr size_t WS_BRELB   = WS_BPADB   + (1024 * 768) / 2;       // 64x768 u16
constexpr size_t WS_TOKPB   = WS_BRELB   + (64 * 768) / 2;         // 2x1024x768 u16
constexpr size_t WS_RELPF   = WS_TOKPB   + (2 * 1024 * 768) / 2;   // 64x768 f32
constexpr size_t WS_RELPB   = WS_RELPF   + 64 * 768;
constexpr size_t WS_HGPF    = WS_RELPB   + 64 * 768;               // 4x768 f32
constexpr size_t WS_HGPB    = WS_HGPF    + 4 * 768;
constexpr size_t WS_DD      = WS_HGPB    + 4 * 768;                // 4x1024 f32 (d4..d7)
constexpr size_t WS_UA      = WS_DD      + 4 * 1024;               // 4x768 f32
constexpr size_t WS_UB      = WS_UA      + 4 * 768;                // 4x768 f32
constexpr size_t WS_CC      = WS_UB      + 4 * 768;                // 8 f32
constexpr size_t WS_FMASK   = WS_CC      + 8;
constexpr size_t WS_BMASK   = WS_FMASK   + 1024;
constexpr size_t WS_C4      = WS_BMASK   + 1024;
constexpr size_t WS_C5      = WS_C4 + 256;
constexpr size_t WS_C6      = WS_C5 + 256;
constexpr size_t WS_C7      = WS_C6 + 256;
constexpr size_t WS_AUX     = WS_C7 + 256;      // int region: jbuf/rankbuf/validbuf

__device__ inline float fast_rcp(float x) {
#if __has_builtin(__builtin_amdgcn_rcpf)
    return __builtin_amdgcn_rcpf(x);
#else
    return 1.f / x;
#endif
}
__device__ inline float fast_exp2(float x) {
#if __has_builtin(__builtin_amdgcn_exp2f)
    return __builtin_amdgcn_exp2f(x);
#else
    return __exp2f(x);
#endif
}
__device__ inline u16 f2bf(float x) {   // RNE
    union { float f; unsigned u; } v; v.f = x;
    unsigned r = v.u + 0x7FFFu + ((v.u >> 16) & 1u);
    return (u16)(r >> 16);
}
__device__ inline float bf2f(u16 x) {
    union { unsigned u; float f; } v; v.u = ((unsigned)x) << 16;
    return v.f;
}

// ---- 1. mega-prep ----
// [0,1024) logits+embsB+dd | [1024,1888) Wm2..7 transpose | [1888,2656) gemv pairs
// [2656,2720) relemb cast | [2720,2724) hgs cast | [2724,2788) brel fp32 GEMV | [2788,2796) cc
__global__ __launch_bounds__(256) void k_prep_all(
        const float* __restrict__ embs, const float* __restrict__ rel_embs,
        const float* __restrict__ h_gs, const float* __restrict__ rel_transe,
        const float* __restrict__ fc_w, const float* __restrict__ fc_b,
        const float* __restrict__ Wm, const float* __restrict__ Wb,
        const float* __restrict__ rproj_w, const float* __restrict__ rproj_b,
        float* __restrict__ out, u16* __restrict__ embsB,
        u16* __restrict__ relembB, u16* __restrict__ hgsB, u16* __restrict__ brelB,
        u16* __restrict__ WtAll,
        float* __restrict__ uA, float* __restrict__ uB, float* __restrict__ cc,
        float* __restrict__ dd)
{
    __shared__ float sh[64 * 65];
    int bx = blockIdx.x, t = threadIdx.x;
    if (bx < 1024) {
        // per-token: embsB cast + 8 dots (4 exact logits, 4 d-vectors)
        int tok = bx;
        const float* e = embs + (size_t)tok * kH;
        float s[8] = {0, 0, 0, 0, 0, 0, 0, 0};
        for (int h = t; h < kH; h += 256) {
            float x = e[h];
            embsB[(size_t)tok * kH + h] = f2bf(x);
#pragma unroll
            for (int j = 0; j < 8; j++) s[j] += x * fc_w[j * kH + h];
        }
#pragma unroll
        for (int off = 32; off; off >>= 1)
#pragma unroll
            for (int j = 0; j < 8; j++) s[j] += __shfl_down(s[j], off, 64);
        float(*red)[4] = (float(*)[4])sh;
        int wid = t >> 6;
        if ((t & 63) == 0) {
#pragma unroll
            for (int j = 0; j < 8; j++) red[j][wid] = s[j];
        }
        __syncthreads();
        if (t == 0) {
            float r[8];
#pragma unroll
            for (int j = 0; j < 8; j++) r[j] = red[j][0] + red[j][1] + red[j][2] + red[j][3];
            out[OFF_FSS + tok] = r[0] + fc_b[0];
            out[OFF_FSE + tok] = r[1] + fc_b[1];
            out[OFF_BOS + tok] = r[2] + fc_b[2];
            out[OFF_BOE + tok] = r[3] + fc_b[3];
            dd[0 * 1024 + tok] = r[4];
            dd[1 * 1024 + tok] = r[5];
            dd[2 * 1024 + tok] = r[6];
            dd[3 * 1024 + tok] = r[7];
        }
    } else if (bx < 1888) {
        // weight transpose Wm2..7: Wt[n][k] = W[k][n]
        int px = bx - 1024;
        int mi = 2 + px / 144, tile = px % 144;
        int kt = (tile / 12) * 64, nt = (tile % 12) * 64;
        const float* src = Wm + (size_t)mi * HH;
        u16* dst = WtAll + (size_t)mi * HH;
        float(*tl)[65] = (float(*)[65])sh;
        int r = t >> 2, cq = (t & 3) * 16;
        int row = kt + r;
#pragma unroll
        for (int q = 0; q < 4; q++) {
            float4 v = *(const float4*)(src + (size_t)row * kH + nt + cq + q * 4);
            tl[r][cq + q * 4 + 0] = v.x;
            tl[r][cq + q * 4 + 1] = v.y;
            tl[r][cq + q * 4 + 2] = v.z;
            tl[r][cq + q * 4 + 3] = v.w;
        }
        __syncthreads();
        u16* drow = dst + (size_t)(nt + r) * kH + kt + cq;
#pragma unroll
        for (int j = 0; j < 16; j++) drow[j] = f2bf(tl[cq + j][r]);
    } else if (bx < 2656) {
        // GEMV pairs: p=0:Wm0@{w4,w5}->uA01  p=1:Wm1@{w6,w7}->uA23
        //             p=2:Wm8@{w4,w5}+w->uB01  p=3:Wm9@{w6,w7}+w->uB23
        int gx = bx - 1888;
        int p = gx / 192;
        int wid = t >> 6, lane = t & 63;
        int row = (gx % 192) * 4 + wid;
        const int wmI[4] = {0, 1, 8, 9};
        const float* W  = Wm + (size_t)wmI[p] * HH + (size_t)row * kH;
        const float* wa = fc_w + (size_t)((p & 1) ? 6 : 4) * kH;
        const float* wb = wa + kH;
        float sa = 0.f, sb = 0.f;
        for (int c = lane; c < kH; c += 64) {
            float wv = W[c];
            sa += wv * wa[c];
            sb += wv * wb[c];
        }
#pragma unroll
        for (int off = 32; off; off >>= 1) {
            sa += __shfl_xor(sa, off, 64);
            sb += __shfl_xor(sb, off, 64);
        }
        if (lane == 0) {
            if (p < 2) {
                uA[(2 * p) * kH + row]     = sa;
                uA[(2 * p + 1) * kH + row] = sb;
            } else {
                int q = p - 2;
                uB[(2 * q) * kH + row]     = sa + wa[row];
                uB[(2 * q + 1) * kH + row] = sb + wb[row];
            }
        }
    } else if (bx < 2720) {
        int r = bx - 2656;
        for (int h = t; h < kH; h += 256) relembB[r * kH + h] = f2bf(rel_embs[r * kH + h]);
    } else if (bx < 2724) {
        int r = bx - 2720;
        for (int h = t; h < kH; h += 256) hgsB[r * kH + h] = f2bf(h_gs[r * kH + h]);
    } else if (bx < 2788) {
        // brel row r: fp32 GEMV rel_transe[r] @ rproj_w + rproj_b -> bf16
        int r = bx - 2724;
        if (t < kTE) sh[t] = rel_transe[r * kTE + t];
        __syncthreads();
        float a0 = rproj_b[t], a1 = rproj_b[t + 256], a2 = rproj_b[t + 512];
        for (int k = 0; k < kTE; k++) {
            float rv = sh[k];
            const float* wr = rproj_w + (size_t)k * kH;
            a0 = fmaf(rv, wr[t], a0);
            a1 = fmaf(rv, wr[t + 256], a1);
            a2 = fmaf(rv, wr[t + 512], a2);
        }
        brelB[r * kH + t]       = f2bf(a0);
        brelB[r * kH + t + 256] = f2bf(a1);
        brelB[r * kH + t + 512] = f2bf(a2);
    } else {
        // cc[j] = Wb[{0,0,1,1,8,8,9,9}[j]] . fc_w[{4,5,6,7,...}[j]]
        int j = bx - 2788;
        const int wbI[8] = {0, 0, 1, 1, 8, 8, 9, 9};
        const int fcI[8] = {4, 5, 6, 7, 4, 5, 6, 7};
        const float* wb = Wb + (size_t)wbI[j] * kH;
        const float* w  = fc_w + (size_t)fcI[j] * kH;
        float s = 0.f;
        for (int h = t; h < kH; h += 256) s += wb[h] * w[h];
#pragma unroll
        for (int off = 32; off; off >>= 1) s += __shfl_down(s, off, 64);
        int wid = t >> 6;
        if ((t & 63) == 0) sh[wid] = s;
        __syncthreads();
        if (t == 0) cc[j] = sh[0] + sh[1] + sh[2] + sh[3];
    }
}

// ---- 2. span extraction metadata (8 blocks, LDS scans) ----
__global__ __launch_bounds__(256) void k_extract_meta(const float* __restrict__ out,
        int* __restrict__ jbuf, int* __restrict__ rankbuf, int* __restrict__ validbuf,
        float* __restrict__ fmask, float* __restrict__ bmask)
{
    int which = blockIdx.x >> 2;
    int b = blockIdx.x & 3;
    int i = threadIdx.x;
    const float* slog = out + (which ? OFF_BOS : OFF_FSS) + (size_t)b * kL;
    const float* elog = out + (which ? OFF_BOE : OFF_FSE) + (size_t)b * kL;
    float sv = slog[i], ev = elog[i];
    bool st = (1.f / (1.f + __expf(-sv)) > 0.5f);
    bool en = (1.f / (1.f + __expf(-ev)) > 0.5f);

    __shared__ int sm[kL];
    __shared__ int ps[kL];
    sm[i] = en ? i : kL;
    __syncthreads();
    for (int step = 1; step < kL; step <<= 1) {  // suffix min
        int v = (i + step < kL) ? sm[i + step] : kL;
        __syncthreads();
        sm[i] = min(sm[i], v);
        __syncthreads();
    }
    int next_end = sm[i];
    int validi = (st && next_end < kL) ? 1 : 0;
    ps[i] = validi;
    __syncthreads();
    for (int step = 1; step < kL; step <<= 1) {  // inclusive prefix sum
        int v = (i >= step) ? ps[i - step] : 0;
        __syncthreads();
        ps[i] += v;
        __syncthreads();
    }
    int rank = ps[i] - 1;
    int num = ps[kL - 1];
    int gbase = (which * kB + b) * kL + i;
    jbuf[gbase] = min(next_end, kL - 1);
    rankbuf[gbase] = rank;
    validbuf[gbase] = validi;
    (which ? bmask : fmask)[b * kL + i] = (i < num) ? 1.f : 0.f;
}

// ---- 3. fused span-means + batched MFMA GEMM (single launch) ----
// blocks [0,2048): span means; [2048,2480): 64x64 GEMM tiles (flat-mapped).
struct GemmJob {
    const u16* A; const u16* Wt; const float* bias;
    float* C; u16* Cbf; const float* rowmask;
    int M; int K; int ldc; int coff;
};
struct GemmBatch { GemmJob j[6]; };

__device__ inline int swz(int row, int slot) {   // short-index into [row][64] layout
    return row * 64 + ((slot ^ (row & 7)) << 3);
}

__global__ __launch_bounds__(256) void k_span_gemm(GemmBatch batch,
        const float* __restrict__ embs,
        const int* __restrict__ jbuf, const int* __restrict__ rankbuf,
        const int* __restrict__ validbuf,
        u16* __restrict__ fpadB, u16* __restrict__ bpadB)
{
    __shared__ short Als[2][64 * 64];      // 16 KB
    __shared__ short Bls[2][64 * 64];      // 16 KB
    int bx = blockIdx.x;
    if (bx < 2048) {
        // ---- span mean ----
        int which = bx >> 10;
        int b = (bx >> 8) & 3;
        int i = bx & 255;
        int gbase = (which * kB + b) * kL + i;
        if (!validbuf[gbase]) return;
        int j = jbuf[gbase];
        int rk = rankbuf[gbase];
        int len = j - i + 1;
        float inv = 1.f / (float)len;
        u16* pad = (which ? bpadB : fpadB) + ((size_t)(b * kL + rk)) * kH;
        const float* e = embs + ((size_t)(b * kL + i)) * kH;
        for (int h = threadIdx.x; h < kH; h += 256) {
            float s = 0.f;
            for (int row = 0; row < len; row++) s += e[(size_t)row * kH + h];
            pad[h] = f2bf(s * inv);
        }
        return;
    }
    // ---- GEMM tile: flat index -> (job, m-tile, n-tile) ----
    int g = bx - 2048;
    int jz, mx, ny;
    if (g < 48)       { jz = g / 12;            mx = 0;             ny = g % 12; }
    else if (g < 240) { jz = 4;                 mx = (g - 48) / 12; ny = (g - 48) % 12; }
    else              { jz = 5;                 mx = (g - 240) / 12; ny = (g - 240) % 12; }
    GemmJob jb = batch.j[jz];

    int tid = threadIdx.x;
    int m0 = mx * 64;
    int n0 = ny * 64;
    int w = tid >> 6, lane = tid & 63;
    int wm = (w >> 1) * 32, wn = (w & 1) * 32;   // 2M x 2N waves, each 32x32
    int lrow = lane & 15, lhi = lane >> 4;
    int srow = tid >> 2, sc0 = tid & 3;          // chunks sc0 and sc0+4
    int K = jb.K;
    int T = K >> 6;

    f32x4 zero4 = {0.f, 0.f, 0.f, 0.f};
    f32x4 acc[2][2];
#pragma unroll
    for (int i = 0; i < 2; i++)
#pragma unroll
        for (int j = 0; j < 2; j++) acc[i][j] = zero4;

    bf16x8 pa[2], pb[2];

#define LOADT(k0)                                                                 \
    {                                                                             \
        _Pragma("unroll")                                                         \
        for (int q = 0; q < 2; q++) {                                             \
            bf16x8 va;                                                            \
            _Pragma("unroll") for (int z = 0; z < 8; z++) va[z] = 0;              \
            if (m0 + srow < jb.M)                                                 \
                va = *reinterpret_cast<const bf16x8*>(                            \
                    jb.A + (size_t)(m0 + srow) * K + (k0) + (sc0 + q * 4) * 8);   \
            pa[q] = va;                                                           \
            pb[q] = *reinterpret_cast<const bf16x8*>(                             \
                jb.Wt + (size_t)(n0 + srow) * K + (k0) + (sc0 + q * 4) * 8);      \
        }                                                                         \
    }
#define STORET(buf)                                                               \
    {                                                                             \
        _Pragma("unroll")                                                         \
        for (int q = 0; q < 2; q++) {                                             \
            *reinterpret_cast<bf16x8*>(&Als[buf][swz(srow, sc0 + q * 4)]) = pa[q];\
            *reinterpret_cast<bf16x8*>(&Bls[buf][swz(srow, sc0 + q * 4)]) = pb[q];\
        }                                                                         \
    }

    LOADT(0);
    STORET(0);
    __syncthreads();
    int cur = 0;
    for (int t = 0; t < T; t++) {
        if (t + 1 < T) LOADT((t + 1) << 6);
#pragma unroll
        for (int sub = 0; sub < 2; sub++) {
            bf16x8 af[2], bg[2];
#pragma unroll
            for (int i = 0; i < 2; i++) {
                af[i] = *reinterpret_cast<const bf16x8*>(
                    &Als[cur][swz(wm + i * 16 + lrow, sub * 4 + lhi)]);
                bg[i] = *reinterpret_cast<const bf16x8*>(
                    &Bls[cur][swz(wn + i * 16 + lrow, sub * 4 + lhi)]);
            }
#pragma unroll
            for (int i = 0; i < 2; i++)
#pragma unroll
                for (int j = 0; j < 2; j++)
                    acc[i][j] = __builtin_amdgcn_mfma_f32_16x16x32_bf16(af[i], bg[j], acc[i][j], 0, 0, 0);
        }
        if (t + 1 < T) STORET(cur ^ 1);
        __syncthreads();
        cur ^= 1;
    }
#undef LOADT
#undef STORET

#pragma unroll
    for (int i = 0; i < 2; i++) {
#pragma unroll
        for (int j = 0; j < 2; j++) {
            int n = n0 + wn + j * 16 + lrow;
            float bi = jb.bias[n];
#pragma unroll
            for (int q = 0; q < 4; q++) {
                int m = m0 + wm + i * 16 + lhi * 4 + q;
                if (m < jb.M) {
                    float val = acc[i][j][q] + bi;
                    if (jb.rowmask) val = (jb.rowmask[m] != 0.f) ? val : 0.f;
                    if (jb.C)   jb.C[(size_t)m * jb.ldc + jb.coff + n] = val;
                    if (jb.Cbf) jb.Cbf[(size_t)m * jb.ldc + jb.coff + n] = f2bf(val);
                }
            }
        }
    }
}

// ---- 4. attention: scores + softmax + c-dots fused; block=(which,b,r) ----
__global__ __launch_bounds__(512) void k_score(const u16* __restrict__ tokpB,
        const float* __restrict__ relpf, const float* __restrict__ relpb,
        const float* __restrict__ hgpf, const float* __restrict__ hgpb,
        const float* __restrict__ V_w, const float* __restrict__ V_b,
        const float* __restrict__ dd,
        float* __restrict__ c4, float* __restrict__ c5,
        float* __restrict__ c6, float* __restrict__ c7)
{
    constexpr float C = 2.8853900817779268f;   // 2*log2(e)
    int idx = blockIdx.x;            // 512
    int which = idx >> 8, b = (idx >> 6) & 3, r = idx & 63;
    int tid = threadIdx.x;
    int wid = tid >> 6, lane = tid & 63;
    int h0 = lane * 12;
    const float* relp = (which ? relpb : relpf) + (size_t)r * kH + h0;
    const float* hgp  = (which ? hgpb : hgpf) + (size_t)b * kH + h0;
    const float* vw   = V_w + h0;

    __shared__ float sc[kL];
    __shared__ float red2[2][8];

    float av2[12], w2[12], wsum = 0.f;
#pragma unroll
    for (int j = 0; j < 12; j++) {
        av2[j] = C * (relp[j] + hgp[j]);
        float wv = vw[j];
        w2[j] = -2.f * wv;
        wsum += wv;
    }
    float vb = V_b[0];
    const u16* base = tokpB + ((size_t)which * (kB * kL) + b * kL) * kH + h0;

    int l0 = wid * 32;
    bf16x4 t0 = *reinterpret_cast<const bf16x4*>(base + (size_t)l0 * kH);
    bf16x4 t1 = *reinterpret_cast<const bf16x4*>(base + (size_t)l0 * kH + 4);
    bf16x4 t2 = *reinterpret_cast<const bf16x4*>(base + (size_t)l0 * kH + 8);
    for (int l = l0; l < l0 + 32; l++) {
        bf16x4 n0, n1, n2;
        if (l + 1 < l0 + 32) {
            const u16* nrow = base + (size_t)(l + 1) * kH;
            n0 = *reinterpret_cast<const bf16x4*>(nrow);
            n1 = *reinterpret_cast<const bf16x4*>(nrow + 4);
            n2 = *reinterpret_cast<const bf16x4*>(nrow + 8);
        }
        float acc = wsum;
#pragma unroll
        for (int j = 0; j < 4; j++) {
            float e0 = fast_exp2(fmaf(bf2f((u16)t0[j]), C, av2[j]));
            acc = fmaf(w2[j], fast_rcp(e0 + 1.f), acc);
            float e1 = fast_exp2(fmaf(bf2f((u16)t1[j]), C, av2[4 + j]));
            acc = fmaf(w2[4 + j], fast_rcp(e1 + 1.f), acc);
            float e2 = fast_exp2(fmaf(bf2f((u16)t2[j]), C, av2[8 + j]));
            acc = fmaf(w2[8 + j], fast_rcp(e2 + 1.f), acc);
        }
#pragma unroll
        for (int off = 32; off; off >>= 1) acc += __shfl_xor(acc, off, 64);
        if (lane == 0) sc[l] = acc + vb;
        t0 = n0; t1 = n1; t2 = n2;
    }
    __syncthreads();

    // softmax over sc[0..255] + c-dots (A never materialized)
    int l = tid & 255;
    bool act = tid < 256;
    float x = act ? sc[l] : -3.4e38f;
    float m = x;
#pragma unroll
    for (int off = 32; off; off >>= 1) m = fmaxf(m, __shfl_xor(m, off, 64));
    if (lane == 0) red2[0][wid] = m;
    __syncthreads();
    m = fmaxf(fmaxf(red2[0][0], red2[0][1]), fmaxf(red2[0][2], red2[0][3]));
    float p = act ? __expf(x - m) : 0.f;
    float s = p;
#pragma unroll
    for (int off = 32; off; off >>= 1) s += __shfl_xor(s, off, 64);
    __syncthreads();
    if (lane == 0) red2[0][wid] = s;
    __syncthreads();
    s = red2[0][0] + red2[0][1] + red2[0][2] + red2[0][3];
    float a = p / s;
    const float* dA = dd + (size_t)(which ? 2 : 0) * 1024 + b * 256;
    const float* dB = dd + (size_t)(which ? 3 : 1) * 1024 + b * 256;
    float q0 = act ? a * dA[l] : 0.f;
    float q1 = act ? a * dB[l] : 0.f;
#pragma unroll
    for (int off = 32; off; off >>= 1) {
        q0 += __shfl_xor(q0, off, 64);
        q1 += __shfl_xor(q1, off, 64);
    }
    __syncthreads();
    if (lane == 0) { red2[0][wid] = q0; red2[1][wid] = q1; }
    __syncthreads();
    if (tid == 0) {
        float r0 = red2[0][0] + red2[0][1] + red2[0][2] + red2[0][3];
        float r1 = red2[1][0] + red2[1][1] + red2[1][2] + red2[1][3];
        if (which) { c6[b * kR + r] = r0; c7[b * kR + r] = r1; }
        else       { c4[b * kR + r] = r0; c5[b * kR + r] = r1; }
    }
}

// ---- 5. t vectors (GEMV decomposition) + fused final broadcast-add ----
__global__ __launch_bounds__(256) void k_t_final(const float* __restrict__ embs,
        const u16* __restrict__ fpadB, const u16* __restrict__ bpadB,
        const float* __restrict__ uA, const float* __restrict__ uB,
        const float* __restrict__ cc,
        const float* __restrict__ fmask, const float* __restrict__ bmask,
        const float* __restrict__ c4, const float* __restrict__ c5,
        const float* __restrict__ c6, const float* __restrict__ c7,
        const float* __restrict__ fc_b, float* __restrict__ out)
{
    int t = blockIdx.x;               // 1024
    int b = t >> 8;
    size_t base = (size_t)t * kH;
    float a4 = 0, a5 = 0, a6 = 0, a7 = 0, f4 = 0, f5 = 0, b6 = 0, b7 = 0;
    for (int h = threadIdx.x; h < kH; h += 256) {
        float e = embs[base + h];
        a4 += e * uB[h];
        a5 += e * uB[kH + h];
        a6 += e * uB[2 * kH + h];
        a7 += e * uB[3 * kH + h];
        float fp = bf2f(fpadB[base + h]);
        f4 += fp * uA[h];
        f5 += fp * uA[kH + h];
        float bp = bf2f(bpadB[base + h]);
        b6 += bp * uA[2 * kH + h];
        b7 += bp * uA[3 * kH + h];
    }
#pragma unroll
    for (int off = 32; off; off >>= 1) {
        a4 += __shfl_down(a4, off, 64);
        a5 += __shfl_down(a5, off, 64);
        a6 += __shfl_down(a6, off, 64);
        a7 += __shfl_down(a7, off, 64);
        f4 += __shfl_down(f4, off, 64);
        f5 += __shfl_down(f5, off, 64);
        b6 += __shfl_down(b6, off, 64);
        b7 += __shfl_down(b7, off, 64);
    }
    __shared__ float red[8][4];
    __shared__ float fin[4];
    int wid = threadIdx.x >> 6;
    if ((threadIdx.x & 63) == 0) {
        red[0][wid] = a4; red[1][wid] = a5; red[2][wid] = a6; red[3][wid] = a7;
        red[4][wid] = f4; red[5][wid] = f5; red[6][wid] = b6; red[7][wid] = b7;
    }
    __syncthreads();
    if (threadIdx.x == 0) {
        float ra4 = red[0][0] + red[0][1] + red[0][2] + red[0][3];
        float ra5 = red[1][0] + red[1][1] + red[1][2] + red[1][3];
        float ra6 = red[2][0] + red[2][1] + red[2][2] + red[2][3];
        float ra7 = red[3][0] + red[3][1] + red[3][2] + red[3][3];
        float rf4 = red[4][0] + red[4][1] + red[4][2] + red[4][3];
        float rf5 = red[5][0] + red[5][1] + red[5][2] + red[5][3];
        float rb6 = red[6][0] + red[6][1] + red[6][2] + red[6][3];
        float rb7 = red[7][0] + red[7][1] + red[7][2] + red[7][3];
        bool mf = fmask[t] != 0.f, mb = bmask[t] != 0.f;
        // SELECT: masked pad rows may hold stale/poison bits -> never multiply
        fin[0] = (mf ? (rf4 + cc[0]) : 0.f) + ra4 + cc[4];
        fin[1] = (mf ? (rf5 + cc[1]) : 0.f) + ra5 + cc[5];
        fin[2] = (mb ? (rb6 + cc[2]) : 0.f) + ra6 + cc[6];
        fin[3] = (mb ? (rb7 + cc[3]) : 0.f) + ra7 + cc[7];
    }
    __syncthreads();
    // fused final: each of 256 threads writes one output value (coalesced 64-wide)
    int row = threadIdx.x >> 6, r = threadIdx.x & 63;
    const float* cp = (row == 0) ? c4 : (row == 1) ? c5 : (row == 2) ? c6 : c7;
    size_t off = (row == 0) ? OFF_FOS : (row == 1) ? OFF_FOE : (row == 2) ? OFF_BSS : OFF_BSE;
    out[off + (size_t)t * kR + r] = fin[row] + cp[b * kR + r] + fc_b[4 + row];
}

extern "C" void kernel_launch(void* const* d_in, const int* in_sizes, int n_in,
                              void* d_out, int out_size, void* d_ws, size_t ws_size,
                              hipStream_t stream)
{
    const float* embs       = (const float*)d_in[0];
    const float* h_gs       = (const float*)d_in[1];
    const float* rel_embs   = (const float*)d_in[2];
    const float* rel_transe = (const float*)d_in[3];
    const float* fc_w       = (const float*)d_in[4];
    const float* fc_b       = (const float*)d_in[5];
    const float* Wm         = (const float*)d_in[6];
    const float* Wb         = (const float*)d_in[7];
    const float* V_w        = (const float*)d_in[8];
    const float* V_b        = (const float*)d_in[9];
    const float* rproj_w    = (const float*)d_in[10];
    const float* rproj_b    = (const float*)d_in[11];
    float* out = (float*)d_out;
    float* ws  = (float*)d_ws;

    u16* WtAll   = (u16*)(ws + WS_WTALL);
    u16* embsB   = (u16*)(ws + WS_EMBSB);
    u16* relembB = (u16*)(ws + WS_RELEMBB);
    u16* hgsB    = (u16*)(ws + WS_HGSB);
    u16* fpadB   = (u16*)(ws + WS_FPADB);
    u16* bpadB   = (u16*)(ws + WS_BPADB);
    u16* brelB   = (u16*)(ws + WS_BRELB);
    u16* tokpB   = (u16*)(ws + WS_TOKPB);
    float* relpf = ws + WS_RELPF;
    float* relpb = ws + WS_RELPB;
    float* hgpf  = ws + WS_HGPF;
    float* hgpb  = ws + WS_HGPB;
    float* dd    = ws + WS_DD;
    float* uA    = ws + WS_UA;
    float* uB    = ws + WS_UB;
    float* cc    = ws + WS_CC;
    float* fmask = ws + WS_FMASK;
    float* bmask = ws + WS_BMASK;
    float* c4 = ws + WS_C4; float* c5 = ws + WS_C5;
    float* c6 = ws + WS_C6; float* c7 = ws + WS_C7;
    int* jbuf     = (int*)(ws + WS_AUX);
    int* rankbuf  = jbuf + 2 * kB * kL;
    int* validbuf = rankbuf + 2 * kB * kL;

    // 1. mega-prep (everything depending only on inputs, incl. brel fp32 GEMV)
    k_prep_all<<<2796, 256, 0, stream>>>(embs, rel_embs, h_gs, rel_transe,
        fc_w, fc_b, Wm, Wb, rproj_w, rproj_b,
        out, embsB, relembB, hgsB, brelB, WtAll, uA, uB, cc, dd);

    // 2. span extraction metadata
    k_extract_meta<<<2 * kB, 256, 0, stream>>>(out, jbuf, rankbuf, validbuf, fmask, bmask);

    // 3. fused span means + gemmA (relpf, hgpf, hgpb, relpb, tokp x2)
    {
        GemmBatch bt;
        bt.j[0] = { relembB, WtAll + 2 * HH, Wb + 2 * kH, relpf, nullptr, nullptr, kR, kH, kH, 0 };
        bt.j[1] = { hgsB,    WtAll + 3 * HH, Wb + 3 * kH, hgpf,  nullptr, nullptr, kB, kH, kH, 0 };
        bt.j[2] = { hgsB,    WtAll + 6 * HH, Wb + 6 * kH, hgpb,  nullptr, nullptr, kB, kH, kH, 0 };
        bt.j[3] = { brelB,   WtAll + 5 * HH, Wb + 5 * kH, relpb, nullptr, nullptr, kR, kH, kH, 0 };
        bt.j[4] = { embsB,   WtAll + 4 * HH, Wb + 4 * kH, nullptr, tokpB,            nullptr, kB * kL, kH, kH, 0 };
        bt.j[5] = { embsB,   WtAll + 7 * HH, Wb + 7 * kH, nullptr, tokpB + (size_t)kB * kL * kH, nullptr, kB * kL, kH, kH, 0 };
        k_span_gemm<<<2480, 256, 0, stream>>>(bt, embs, jbuf, rankbuf, validbuf, fpadB, bpadB);
    }

    // 4. fused scores + softmax + c-dots
    k_score<<<512, 512, 0, stream>>>(tokpB, relpf, relpb, hgpf, hgpb, V_w, V_b,
                                     dd, c4, c5, c6, c7);

    // 5. t vectors + fused final broadcast-add
    k_t_final<<<kB * kL, 256, 0, stream>>>(embs, fpadB, bpadB, uA, uB, cc, fmask, bmask,
                                           c4, c5, c6, c7, fc_b, out);
}

// Round 13
// 78.696 us; speedup vs baseline: 3.8288x; 1.0037x over previous
//
#include <hip/hip_runtime.h>
#include <cstddef>

using u16 = unsigned short;
typedef __attribute__((ext_vector_type(8))) short bf16x8;
typedef __attribute__((ext_vector_type(4))) short bf16x4;
typedef __attribute__((ext_vector_type(4))) float f32x4;

constexpr int kB = 4, kL = 256, kR = 64, kH = 768, kTE = 100;
constexpr size_t HH = (size_t)kH * kH;

// ---- output offsets (floats) in return order ----
constexpr size_t OFF_FSS = 0;
constexpr size_t OFF_FSE = OFF_FSS + kB * kL;
constexpr size_t OFF_FOS = OFF_FSE + kB * kL;
constexpr size_t OFF_FOE = OFF_FOS + (size_t)kB * kL * kR;
constexpr size_t OFF_BOS = OFF_FOE + (size_t)kB * kL * kR;
constexpr size_t OFF_BOE = OFF_BOS + kB * kL;
constexpr size_t OFF_BSS = OFF_BOE + kB * kL;
constexpr size_t OFF_BSE = OFF_BSS + (size_t)kB * kL * kR;

// ---- workspace layout (float units), no aliasing ----
constexpr size_t WS_WTALL   = 0;                                   // 10xHH u16 (2..7 used)
constexpr size_t WS_EMBSB   = WS_WTALL   + 10 * HH / 2;            // 1024x768 u16
constexpr size_t WS_RELEMBB = WS_EMBSB   + (1024 * 768) / 2;       // 64x768 u16
constexpr size_t WS_HGSB    = WS_RELEMBB + (64 * 768) / 2;         // 4x768 u16
constexpr size_t WS_FPADB   = WS_HGSB    + (4 * 768) / 2;          // 1024x768 u16
constexpr size_t WS_BPADB   = WS_FPADB   + (1024 * 768) / 2;       // 1024x768 u16
constexpr size_t WS_BRELB   = WS_BPADB   + (1024 * 768) / 2;       // 64x768 u16
constexpr size_t WS_TOKPB   = WS_BRELB   + (64 * 768) / 2;         // 2x1024x768 u16
constexpr size_t WS_RELPF   = WS_TOKPB   + (2 * 1024 * 768) / 2;   // 64x768 f32
constexpr size_t WS_RELPB   = WS_RELPF   + 64 * 768;
constexpr size_t WS_HGPF    = WS_RELPB   + 64 * 768;               // 4x768 f32
constexpr size_t WS_HGPB    = WS_HGPF    + 4 * 768;
constexpr size_t WS_DD      = WS_HGPB    + 4 * 768;                // 4x1024 f32 (d4..d7)
constexpr size_t WS_UA      = WS_DD      + 4 * 1024;               // 4x768 f32
constexpr size_t WS_UB      = WS_UA      + 4 * 768;                // 4x768 f32
constexpr size_t WS_CC      = WS_UB      + 4 * 768;                // 8 f32
constexpr size_t WS_FMASK   = WS_CC      + 8;
constexpr size_t WS_BMASK   = WS_FMASK   + 1024;
constexpr size_t WS_C4      = WS_BMASK   + 1024;
constexpr size_t WS_C5      = WS_C4 + 256;
constexpr size_t WS_C6      = WS_C5 + 256;
constexpr size_t WS_C7      = WS_C6 + 256;

__device__ inline float fast_rcp(float x) {
#if __has_builtin(__builtin_amdgcn_rcpf)
    return __builtin_amdgcn_rcpf(x);
#else
    return 1.f / x;
#endif
}
__device__ inline float fast_exp2(float x) {
#if __has_builtin(__builtin_amdgcn_exp2f)
    return __builtin_amdgcn_exp2f(x);
#else
    return __exp2f(x);
#endif
}
__device__ inline u16 f2bf(float x) {   // RNE
    union { float f; unsigned u; } v; v.f = x;
    unsigned r = v.u + 0x7FFFu + ((v.u >> 16) & 1u);
    return (u16)(r >> 16);
}
__device__ inline float bf2f(u16 x) {
    union { unsigned u; float f; } v; v.u = ((unsigned)x) << 16;
    return v.f;
}

// ---- 1. mega-prep ----
// [0,1024) logits+embsB+dd | [1024,1888) Wm2..7 transpose | [1888,2656) gemv pairs
// [2656,2720) relemb cast | [2720,2724) hgs cast | [2724,2788) brel fp32 GEMV | [2788,2796) cc
__global__ __launch_bounds__(256) void k_prep_all(
        const float* __restrict__ embs, const float* __restrict__ rel_embs,
        const float* __restrict__ h_gs, const float* __restrict__ rel_transe,
        const float* __restrict__ fc_w, const float* __restrict__ fc_b,
        const float* __restrict__ Wm, const float* __restrict__ Wb,
        const float* __restrict__ rproj_w, const float* __restrict__ rproj_b,
        float* __restrict__ out, u16* __restrict__ embsB,
        u16* __restrict__ relembB, u16* __restrict__ hgsB, u16* __restrict__ brelB,
        u16* __restrict__ WtAll,
        float* __restrict__ uA, float* __restrict__ uB, float* __restrict__ cc,
        float* __restrict__ dd)
{
    __shared__ float sh[64 * 65];
    int bx = blockIdx.x, t = threadIdx.x;
    if (bx < 1024) {
        // per-token: embsB cast + 8 dots (4 exact logits, 4 d-vectors)
        int tok = bx;
        const float* e = embs + (size_t)tok * kH;
        float s[8] = {0, 0, 0, 0, 0, 0, 0, 0};
        for (int h = t; h < kH; h += 256) {
            float x = e[h];
            embsB[(size_t)tok * kH + h] = f2bf(x);
#pragma unroll
            for (int j = 0; j < 8; j++) s[j] += x * fc_w[j * kH + h];
        }
#pragma unroll
        for (int off = 32; off; off >>= 1)
#pragma unroll
            for (int j = 0; j < 8; j++) s[j] += __shfl_down(s[j], off, 64);
        float(*red)[4] = (float(*)[4])sh;
        int wid = t >> 6;
        if ((t & 63) == 0) {
#pragma unroll
            for (int j = 0; j < 8; j++) red[j][wid] = s[j];
        }
        __syncthreads();
        if (t == 0) {
            float r[8];
#pragma unroll
            for (int j = 0; j < 8; j++) r[j] = red[j][0] + red[j][1] + red[j][2] + red[j][3];
            out[OFF_FSS + tok] = r[0] + fc_b[0];
            out[OFF_FSE + tok] = r[1] + fc_b[1];
            out[OFF_BOS + tok] = r[2] + fc_b[2];
            out[OFF_BOE + tok] = r[3] + fc_b[3];
            dd[0 * 1024 + tok] = r[4];
            dd[1 * 1024 + tok] = r[5];
            dd[2 * 1024 + tok] = r[6];
            dd[3 * 1024 + tok] = r[7];
        }
    } else if (bx < 1888) {
        // weight transpose Wm2..7: Wt[n][k] = W[k][n]
        int px = bx - 1024;
        int mi = 2 + px / 144, tile = px % 144;
        int kt = (tile / 12) * 64, nt = (tile % 12) * 64;
        const float* src = Wm + (size_t)mi * HH;
        u16* dst = WtAll + (size_t)mi * HH;
        float(*tl)[65] = (float(*)[65])sh;
        int r = t >> 2, cq = (t & 3) * 16;
        int row = kt + r;
#pragma unroll
        for (int q = 0; q < 4; q++) {
            float4 v = *(const float4*)(src + (size_t)row * kH + nt + cq + q * 4);
            tl[r][cq + q * 4 + 0] = v.x;
            tl[r][cq + q * 4 + 1] = v.y;
            tl[r][cq + q * 4 + 2] = v.z;
            tl[r][cq + q * 4 + 3] = v.w;
        }
        __syncthreads();
        u16* drow = dst + (size_t)(nt + r) * kH + kt + cq;
#pragma unroll
        for (int j = 0; j < 16; j++) drow[j] = f2bf(tl[cq + j][r]);
    } else if (bx < 2656) {
        // GEMV pairs: p=0:Wm0@{w4,w5}->uA01  p=1:Wm1@{w6,w7}->uA23
        //             p=2:Wm8@{w4,w5}+w->uB01  p=3:Wm9@{w6,w7}+w->uB23
        int gx = bx - 1888;
        int p = gx / 192;
        int wid = t >> 6, lane = t & 63;
        int row = (gx % 192) * 4 + wid;
        const int wmI[4] = {0, 1, 8, 9};
        const float* W  = Wm + (size_t)wmI[p] * HH + (size_t)row * kH;
        const float* wa = fc_w + (size_t)((p & 1) ? 6 : 4) * kH;
        const float* wb = wa + kH;
        float sa = 0.f, sb = 0.f;
        for (int c = lane; c < kH; c += 64) {
            float wv = W[c];
            sa += wv * wa[c];
            sb += wv * wb[c];
        }
#pragma unroll
        for (int off = 32; off; off >>= 1) {
            sa += __shfl_xor(sa, off, 64);
            sb += __shfl_xor(sb, off, 64);
        }
        if (lane == 0) {
            if (p < 2) {
                uA[(2 * p) * kH + row]     = sa;
                uA[(2 * p + 1) * kH + row] = sb;
            } else {
                int q = p - 2;
                uB[(2 * q) * kH + row]     = sa + wa[row];
                uB[(2 * q + 1) * kH + row] = sb + wb[row];
            }
        }
    } else if (bx < 2720) {
        int r = bx - 2656;
        for (int h = t; h < kH; h += 256) relembB[r * kH + h] = f2bf(rel_embs[r * kH + h]);
    } else if (bx < 2724) {
        int r = bx - 2720;
        for (int h = t; h < kH; h += 256) hgsB[r * kH + h] = f2bf(h_gs[r * kH + h]);
    } else if (bx < 2788) {
        // brel row r: fp32 GEMV rel_transe[r] @ rproj_w + rproj_b -> bf16
        int r = bx - 2724;
        if (t < kTE) sh[t] = rel_transe[r * kTE + t];
        __syncthreads();
        float a0 = rproj_b[t], a1 = rproj_b[t + 256], a2 = rproj_b[t + 512];
        for (int k = 0; k < kTE; k++) {
            float rv = sh[k];
            const float* wr = rproj_w + (size_t)k * kH;
            a0 = fmaf(rv, wr[t], a0);
            a1 = fmaf(rv, wr[t + 256], a1);
            a2 = fmaf(rv, wr[t + 512], a2);
        }
        brelB[r * kH + t]       = f2bf(a0);
        brelB[r * kH + t + 256] = f2bf(a1);
        brelB[r * kH + t + 512] = f2bf(a2);
    } else {
        // cc[j] = Wb[{0,0,1,1,8,8,9,9}[j]] . fc_w[{4,5,6,7,...}[j]]
        int j = bx - 2788;
        const int wbI[8] = {0, 0, 1, 1, 8, 8, 9, 9};
        const int fcI[8] = {4, 5, 6, 7, 4, 5, 6, 7};
        const float* wb = Wb + (size_t)wbI[j] * kH;
        const float* w  = fc_w + (size_t)fcI[j] * kH;
        float s = 0.f;
        for (int h = t; h < kH; h += 256) s += wb[h] * w[h];
#pragma unroll
        for (int off = 32; off; off >>= 1) s += __shfl_down(s, off, 64);
        int wid = t >> 6;
        if ((t & 63) == 0) sh[wid] = s;
        __syncthreads();
        if (t == 0) cc[j] = sh[0] + sh[1] + sh[2] + sh[3];
    }
}

// ---- 2. fused span extraction (scan per block) + span means + batched MFMA GEMM ----
// blocks [0,2048): one span token each (redundant in-LDS scan, write own mask+mean);
// blocks [2048,2480): 64x64 GEMM tiles (flat-mapped).
struct GemmJob {
    const u16* A; const u16* Wt; const float* bias;
    float* C; u16* Cbf; const float* rowmask;
    int M; int K; int ldc; int coff;
};
struct GemmBatch { GemmJob j[6]; };

__device__ inline int swz(int row, int slot) {   // short-index into [row][64] layout
    return row * 64 + ((slot ^ (row & 7)) << 3);
}

__global__ __launch_bounds__(256) void k_span_gemm(GemmBatch batch,
        const float* __restrict__ out, const float* __restrict__ embs,
        float* __restrict__ fmask, float* __restrict__ bmask,
        u16* __restrict__ fpadB, u16* __restrict__ bpadB)
{
    __shared__ short Als[2][64 * 64];      // 16 KB (also aliased by span scan)
    __shared__ short Bls[2][64 * 64];      // 16 KB
    int bx = blockIdx.x;
    if (bx < 2048) {
        // ---- span token (which,b,i0): redundant scan, own mask + mean ----
        int which = bx >> 10;
        int b = (bx >> 8) & 3;
        int i0 = bx & 255;
        int i = threadIdx.x;
        const float* slog = out + (which ? OFF_BOS : OFF_FSS) + (size_t)b * kL;
        const float* elog = out + (which ? OFF_BOE : OFF_FSE) + (size_t)b * kL;
        float sv = slog[i], ev = elog[i];
        bool st = (1.f / (1.f + __expf(-sv)) > 0.5f);
        bool en = (1.f / (1.f + __expf(-ev)) > 0.5f);

        int* sm = (int*)(&Als[0][0]);        // [256]
        int* ps = sm + kL;                   // [256]
        sm[i] = en ? i : kL;
        __syncthreads();
        for (int step = 1; step < kL; step <<= 1) {  // suffix min
            int v = (i + step < kL) ? sm[i + step] : kL;
            __syncthreads();
            sm[i] = min(sm[i], v);
            __syncthreads();
        }
        int next_end = sm[i];                        // final (sm stays)
        ps[i] = (st && next_end < kL) ? 1 : 0;
        __syncthreads();
        for (int step = 1; step < kL; step <<= 1) {  // inclusive prefix sum
            int v = (i >= step) ? ps[i - step] : 0;
            __syncthreads();
            ps[i] += v;
            __syncthreads();
        }
        // own-token metadata (thread i0 holds st for token i0)
        __shared__ int meta[3];   // valid, j, rank
        if (i == i0) {
            int valid0 = (st && next_end < kL) ? 1 : 0;
            meta[0] = valid0;
            meta[1] = min(next_end, kL - 1);
            meta[2] = ps[i0] - 1;
            int num = ps[kL - 1];
            (which ? bmask : fmask)[b * kL + i0] = (i0 < num) ? 1.f : 0.f;
        }
        __syncthreads();
        if (!meta[0]) return;
        int j = meta[1];
        int rk = meta[2];
        int len = j - i0 + 1;
        float inv = 1.f / (float)len;
        u16* pad = (which ? bpadB : fpadB) + ((size_t)(b * kL + rk)) * kH;
        const float* e = embs + ((size_t)(b * kL + i0)) * kH;
        for (int h = threadIdx.x; h < kH; h += 256) {
            float s = 0.f;
            for (int row = 0; row < len; row++) s += e[(size_t)row * kH + h];
            pad[h] = f2bf(s * inv);
        }
        return;
    }
    // ---- GEMM tile: flat index -> (job, m-tile, n-tile) ----
    int g = bx - 2048;
    int jz, mx, ny;
    if (g < 48)       { jz = g / 12;            mx = 0;              ny = g % 12; }
    else if (g < 240) { jz = 4;                 mx = (g - 48) / 12;  ny = (g - 48) % 12; }
    else              { jz = 5;                 mx = (g - 240) / 12; ny = (g - 240) % 12; }
    GemmJob jb = batch.j[jz];

    int tid = threadIdx.x;
    int m0 = mx * 64;
    int n0 = ny * 64;
    int w = tid >> 6, lane = tid & 63;
    int wm = (w >> 1) * 32, wn = (w & 1) * 32;   // 2M x 2N waves, each 32x32
    int lrow = lane & 15, lhi = lane >> 4;
    int srow = tid >> 2, sc0 = tid & 3;          // chunks sc0 and sc0+4
    int K = jb.K;
    int T = K >> 6;

    f32x4 zero4 = {0.f, 0.f, 0.f, 0.f};
    f32x4 acc[2][2];
#pragma unroll
    for (int i = 0; i < 2; i++)
#pragma unroll
        for (int j = 0; j < 2; j++) acc[i][j] = zero4;

    bf16x8 pa[2], pb[2];

#define LOADT(k0)                                                                 \
    {                                                                             \
        _Pragma("unroll")                                                         \
        for (int q = 0; q < 2; q++) {                                             \
            bf16x8 va;                                                            \
            _Pragma("unroll") for (int z = 0; z < 8; z++) va[z] = 0;              \
            if (m0 + srow < jb.M)                                                 \
                va = *reinterpret_cast<const bf16x8*>(                            \
                    jb.A + (size_t)(m0 + srow) * K + (k0) + (sc0 + q * 4) * 8);   \
            pa[q] = va;                                                           \
            pb[q] = *reinterpret_cast<const bf16x8*>(                             \
                jb.Wt + (size_t)(n0 + srow) * K + (k0) + (sc0 + q * 4) * 8);      \
        }                                                                         \
    }
#define STORET(buf)                                                               \
    {                                                                             \
        _Pragma("unroll")                                                         \
        for (int q = 0; q < 2; q++) {                                             \
            *reinterpret_cast<bf16x8*>(&Als[buf][swz(srow, sc0 + q * 4)]) = pa[q];\
            *reinterpret_cast<bf16x8*>(&Bls[buf][swz(srow, sc0 + q * 4)]) = pb[q];\
        }                                                                         \
    }

    LOADT(0);
    STORET(0);
    __syncthreads();
    int cur = 0;
    for (int t = 0; t < T; t++) {
        if (t + 1 < T) LOADT((t + 1) << 6);
#pragma unroll
        for (int sub = 0; sub < 2; sub++) {
            bf16x8 af[2], bg[2];
#pragma unroll
            for (int i = 0; i < 2; i++) {
                af[i] = *reinterpret_cast<const bf16x8*>(
                    &Als[cur][swz(wm + i * 16 + lrow, sub * 4 + lhi)]);
                bg[i] = *reinterpret_cast<const bf16x8*>(
                    &Bls[cur][swz(wn + i * 16 + lrow, sub * 4 + lhi)]);
            }
#pragma unroll
            for (int i = 0; i < 2; i++)
#pragma unroll
                for (int j = 0; j < 2; j++)
                    acc[i][j] = __builtin_amdgcn_mfma_f32_16x16x32_bf16(af[i], bg[j], acc[i][j], 0, 0, 0);
        }
        if (t + 1 < T) STORET(cur ^ 1);
        __syncthreads();
        cur ^= 1;
    }
#undef LOADT
#undef STORET

#pragma unroll
    for (int i = 0; i < 2; i++) {
#pragma unroll
        for (int j = 0; j < 2; j++) {
            int n = n0 + wn + j * 16 + lrow;
            float bi = jb.bias[n];
#pragma unroll
            for (int q = 0; q < 4; q++) {
                int m = m0 + wm + i * 16 + lhi * 4 + q;
                if (m < jb.M) {
                    float val = acc[i][j][q] + bi;
                    if (jb.rowmask) val = (jb.rowmask[m] != 0.f) ? val : 0.f;
                    if (jb.C)   jb.C[(size_t)m * jb.ldc + jb.coff + n] = val;
                    if (jb.Cbf) jb.Cbf[(size_t)m * jb.ldc + jb.coff + n] = f2bf(val);
                }
            }
        }
    }
}

// ---- 3. attention: scores + softmax + c-dots fused; block=(which,b,r) ----
__global__ __launch_bounds__(512) void k_score(const u16* __restrict__ tokpB,
        const float* __restrict__ relpf, const float* __restrict__ relpb,
        const float* __restrict__ hgpf, const float* __restrict__ hgpb,
        const float* __restrict__ V_w, const float* __restrict__ V_b,
        const float* __restrict__ dd,
        float* __restrict__ c4, float* __restrict__ c5,
        float* __restrict__ c6, float* __restrict__ c7)
{
    constexpr float C = 2.8853900817779268f;   // 2*log2(e)
    int idx = blockIdx.x;            // 512
    int which = idx >> 8, b = (idx >> 6) & 3, r = idx & 63;
    int tid = threadIdx.x;
    int wid = tid >> 6, lane = tid & 63;
    int h0 = lane * 12;
    const float* relp = (which ? relpb : relpf) + (size_t)r * kH + h0;
    const float* hgp  = (which ? hgpb : hgpf) + (size_t)b * kH + h0;
    const float* vw   = V_w + h0;

    __shared__ float sc[kL];
    __shared__ float red2[2][8];

    float av2[12], w2[12], wsum = 0.f;
#pragma unroll
    for (int j = 0; j < 12; j++) {
        av2[j] = C * (relp[j] + hgp[j]);
        float wv = vw[j];
        w2[j] = -2.f * wv;
        wsum += wv;
    }
    float vb = V_b[0];
    const u16* base = tokpB + ((size_t)which * (kB * kL) + b * kL) * kH + h0;

    int l0 = wid * 32;
    bf16x4 t0 = *reinterpret_cast<const bf16x4*>(base + (size_t)l0 * kH);
    bf16x4 t1 = *reinterpret_cast<const bf16x4*>(base + (size_t)l0 * kH + 4);
    bf16x4 t2 = *reinterpret_cast<const bf16x4*>(base + (size_t)l0 * kH + 8);
    for (int l = l0; l < l0 + 32; l++) {
        bf16x4 n0, n1, n2;
        if (l + 1 < l0 + 32) {
            const u16* nrow = base + (size_t)(l + 1) * kH;
            n0 = *reinterpret_cast<const bf16x4*>(nrow);
            n1 = *reinterpret_cast<const bf16x4*>(nrow + 4);
            n2 = *reinterpret_cast<const bf16x4*>(nrow + 8);
        }
        float acc = wsum;
#pragma unroll
        for (int j = 0; j < 4; j++) {
            float e0 = fast_exp2(fmaf(bf2f((u16)t0[j]), C, av2[j]));
            acc = fmaf(w2[j], fast_rcp(e0 + 1.f), acc);
            float e1 = fast_exp2(fmaf(bf2f((u16)t1[j]), C, av2[4 + j]));
            acc = fmaf(w2[4 + j], fast_rcp(e1 + 1.f), acc);
            float e2 = fast_exp2(fmaf(bf2f((u16)t2[j]), C, av2[8 + j]));
            acc = fmaf(w2[8 + j], fast_rcp(e2 + 1.f), acc);
        }
#pragma unroll
        for (int off = 32; off; off >>= 1) acc += __shfl_xor(acc, off, 64);
        if (lane == 0) sc[l] = acc + vb;
        t0 = n0; t1 = n1; t2 = n2;
    }
    __syncthreads();

    // softmax over sc[0..255] + c-dots (A never materialized)
    int l = tid & 255;
    bool act = tid < 256;
    float x = act ? sc[l] : -3.4e38f;
    float m = x;
#pragma unroll
    for (int off = 32; off; off >>= 1) m = fmaxf(m, __shfl_xor(m, off, 64));
    if (lane == 0) red2[0][wid] = m;
    __syncthreads();
    m = fmaxf(fmaxf(red2[0][0], red2[0][1]), fmaxf(red2[0][2], red2[0][3]));
    float p = act ? __expf(x - m) : 0.f;
    float s = p;
#pragma unroll
    for (int off = 32; off; off >>= 1) s += __shfl_xor(s, off, 64);
    __syncthreads();
    if (lane == 0) red2[0][wid] = s;
    __syncthreads();
    s = red2[0][0] + red2[0][1] + red2[0][2] + red2[0][3];
    float a = p / s;
    const float* dA = dd + (size_t)(which ? 2 : 0) * 1024 + b * 256;
    const float* dB = dd + (size_t)(which ? 3 : 1) * 1024 + b * 256;
    float q0 = act ? a * dA[l] : 0.f;
    float q1 = act ? a * dB[l] : 0.f;
#pragma unroll
    for (int off = 32; off; off >>= 1) {
        q0 += __shfl_xor(q0, off, 64);
        q1 += __shfl_xor(q1, off, 64);
    }
    __syncthreads();
    if (lane == 0) { red2[0][wid] = q0; red2[1][wid] = q1; }
    __syncthreads();
    if (tid == 0) {
        float r0 = red2[0][0] + red2[0][1] + red2[0][2] + red2[0][3];
        float r1 = red2[1][0] + red2[1][1] + red2[1][2] + red2[1][3];
        if (which) { c6[b * kR + r] = r0; c7[b * kR + r] = r1; }
        else       { c4[b * kR + r] = r0; c5[b * kR + r] = r1; }
    }
}

// ---- 4. t vectors (GEMV decomposition) + fused final broadcast-add ----
__global__ __launch_bounds__(256) void k_t_final(const float* __restrict__ embs,
        const u16* __restrict__ fpadB, const u16* __restrict__ bpadB,
        const float* __restrict__ uA, const float* __restrict__ uB,
        const float* __restrict__ cc,
        const float* __restrict__ fmask, const float* __restrict__ bmask,
        const float* __restrict__ c4, const float* __restrict__ c5,
        const float* __restrict__ c6, const float* __restrict__ c7,
        const float* __restrict__ fc_b, float* __restrict__ out)
{
    int t = blockIdx.x;               // 1024
    int b = t >> 8;
    size_t base = (size_t)t * kH;
    float a4 = 0, a5 = 0, a6 = 0, a7 = 0, f4 = 0, f5 = 0, b6 = 0, b7 = 0;
    for (int h = threadIdx.x; h < kH; h += 256) {
        float e = embs[base + h];
        a4 += e * uB[h];
        a5 += e * uB[kH + h];
        a6 += e * uB[2 * kH + h];
        a7 += e * uB[3 * kH + h];
        float fp = bf2f(fpadB[base + h]);
        f4 += fp * uA[h];
        f5 += fp * uA[kH + h];
        float bp = bf2f(bpadB[base + h]);
        b6 += bp * uA[2 * kH + h];
        b7 += bp * uA[3 * kH + h];
    }
#pragma unroll
    for (int off = 32; off; off >>= 1) {
        a4 += __shfl_down(a4, off, 64);
        a5 += __shfl_down(a5, off, 64);
        a6 += __shfl_down(a6, off, 64);
        a7 += __shfl_down(a7, off, 64);
        f4 += __shfl_down(f4, off, 64);
        f5 += __shfl_down(f5, off, 64);
        b6 += __shfl_down(b6, off, 64);
        b7 += __shfl_down(b7, off, 64);
    }
    __shared__ float red[8][4];
    __shared__ float fin[4];
    int wid = threadIdx.x >> 6;
    if ((threadIdx.x & 63) == 0) {
        red[0][wid] = a4; red[1][wid] = a5; red[2][wid] = a6; red[3][wid] = a7;
        red[4][wid] = f4; red[5][wid] = f5; red[6][wid] = b6; red[7][wid] = b7;
    }
    __syncthreads();
    if (threadIdx.x == 0) {
        float ra4 = red[0][0] + red[0][1] + red[0][2] + red[0][3];
        float ra5 = red[1][0] + red[1][1] + red[1][2] + red[1][3];
        float ra6 = red[2][0] + red[2][1] + red[2][2] + red[2][3];
        float ra7 = red[3][0] + red[3][1] + red[3][2] + red[3][3];
        float rf4 = red[4][0] + red[4][1] + red[4][2] + red[4][3];
        float rf5 = red[5][0] + red[5][1] + red[5][2] + red[5][3];
        float rb6 = red[6][0] + red[6][1] + red[6][2] + red[6][3];
        float rb7 = red[7][0] + red[7][1] + red[7][2] + red[7][3];
        bool mf = fmask[t] != 0.f, mb = bmask[t] != 0.f;
        // SELECT: masked pad rows may hold stale/poison bits -> never multiply
        fin[0] = (mf ? (rf4 + cc[0]) : 0.f) + ra4 + cc[4];
        fin[1] = (mf ? (rf5 + cc[1]) : 0.f) + ra5 + cc[5];
        fin[2] = (mb ? (rb6 + cc[2]) : 0.f) + ra6 + cc[6];
        fin[3] = (mb ? (rb7 + cc[3]) : 0.f) + ra7 + cc[7];
    }
    __syncthreads();
    // fused final: each of 256 threads writes one output value (coalesced 64-wide)
    int row = threadIdx.x >> 6, r = threadIdx.x & 63;
    const float* cp = (row == 0) ? c4 : (row == 1) ? c5 : (row == 2) ? c6 : c7;
    size_t off = (row == 0) ? OFF_FOS : (row == 1) ? OFF_FOE : (row == 2) ? OFF_BSS : OFF_BSE;
    out[off + (size_t)t * kR + r] = fin[row] + cp[b * kR + r] + fc_b[4 + row];
}

extern "C" void kernel_launch(void* const* d_in, const int* in_sizes, int n_in,
                              void* d_out, int out_size, void* d_ws, size_t ws_size,
                              hipStream_t stream)
{
    const float* embs       = (const float*)d_in[0];
    const float* h_gs       = (const float*)d_in[1];
    const float* rel_embs   = (const float*)d_in[2];
    const float* rel_transe = (const float*)d_in[3];
    const float* fc_w       = (const float*)d_in[4];
    const float* fc_b       = (const float*)d_in[5];
    const float* Wm         = (const float*)d_in[6];
    const float* Wb         = (const float*)d_in[7];
    const float* V_w        = (const float*)d_in[8];
    const float* V_b        = (const float*)d_in[9];
    const float* rproj_w    = (const float*)d_in[10];
    const float* rproj_b    = (const float*)d_in[11];
    float* out = (float*)d_out;
    float* ws  = (float*)d_ws;

    u16* WtAll   = (u16*)(ws + WS_WTALL);
    u16* embsB   = (u16*)(ws + WS_EMBSB);
    u16* relembB = (u16*)(ws + WS_RELEMBB);
    u16* hgsB    = (u16*)(ws + WS_HGSB);
    u16* fpadB   = (u16*)(ws + WS_FPADB);
    u16* bpadB   = (u16*)(ws + WS_BPADB);
    u16* brelB   = (u16*)(ws + WS_BRELB);
    u16* tokpB   = (u16*)(ws + WS_TOKPB);
    float* relpf = ws + WS_RELPF;
    float* relpb = ws + WS_RELPB;
    float* hgpf  = ws + WS_HGPF;
    float* hgpb  = ws + WS_HGPB;
    float* dd    = ws + WS_DD;
    float* uA    = ws + WS_UA;
    float* uB    = ws + WS_UB;
    float* cc    = ws + WS_CC;
    float* fmask = ws + WS_FMASK;
    float* bmask = ws + WS_BMASK;
    float* c4 = ws + WS_C4; float* c5 = ws + WS_C5;
    float* c6 = ws + WS_C6; float* c7 = ws + WS_C7;

    // 1. mega-prep (everything depending only on inputs, incl. brel fp32 GEMV)
    k_prep_all<<<2796, 256, 0, stream>>>(embs, rel_embs, h_gs, rel_transe,
        fc_w, fc_b, Wm, Wb, rproj_w, rproj_b,
        out, embsB, relembB, hgsB, brelB, WtAll, uA, uB, cc, dd);

    // 2. fused span extraction (in-block scan) + span means + gemmA
    {
        GemmBatch bt;
        bt.j[0] = { relembB, WtAll + 2 * HH, Wb + 2 * kH, relpf, nullptr, nullptr, kR, kH, kH, 0 };
        bt.j[1] = { hgsB,    WtAll + 3 * HH, Wb + 3 * kH, hgpf,  nullptr, nullptr, kB, kH, kH, 0 };
        bt.j[2] = { hgsB,    WtAll + 6 * HH, Wb + 6 * kH, hgpb,  nullptr, nullptr, kB, kH, kH, 0 };
        bt.j[3] = { brelB,   WtAll + 5 * HH, Wb + 5 * kH, relpb, nullptr, nullptr, kR, kH, kH, 0 };
        bt.j[4] = { embsB,   WtAll + 4 * HH, Wb + 4 * kH, nullptr, tokpB,            nullptr, kB * kL, kH, kH, 0 };
        bt.j[5] = { embsB,   WtAll + 7 * HH, Wb + 7 * kH, nullptr, tokpB + (size_t)kB * kL * kH, nullptr, kB * kL, kH, kH, 0 };
        k_span_gemm<<<2480, 256, 0, stream>>>(bt, out, embs, fmask, bmask, fpadB, bpadB);
    }

    // 3. fused scores + softmax + c-dots
    k_score<<<512, 512, 0, stream>>>(tokpB, relpf, relpb, hgpf, hgpb, V_w, V_b,
                                     dd, c4, c5, c6, c7);

    // 4. t vectors + fused final broadcast-add
    k_t_final<<<kB * kL, 256, 0, stream>>>(embs, fpadB, bpadB, uA, uB, cc, fmask, bmask,
                                           c4, c5, c6, c7, fc_b, out);
}